// Round 1
// 875.691 us; speedup vs baseline: 1.0052x; 1.0052x over previous
//
#include <hip/hip_runtime.h>

// ---------------- types / helpers ----------------
typedef unsigned short u16;
typedef __bf16 bf16x8 __attribute__((ext_vector_type(8)));
typedef float floatx4 __attribute__((ext_vector_type(4)));

#define DIM 512
#define HEADS 8
#define DH 64
#define SEQ 4096
#define BATCH 2
#define ROWS (BATCH * SEQ) /* 8192 */
#define FFDIM 2048
#define QKVW 1536 /* fused qkv row width */
#define LSTRIDE 3145728L /* repacked weight elems per layer */

__device__ __forceinline__ float b2f(u16 u) {
  union { float f; unsigned int i; } c; c.i = ((unsigned int)u) << 16; return c.f;
}
__device__ __forceinline__ u16 f2b(float f) {
  union { float f; unsigned int i; } c; c.f = f;
  unsigned int r = c.i + 0x7FFFu + ((c.i >> 16) & 1u);
  return (u16)(r >> 16);
}
__device__ __forceinline__ float ldin(const void* p, long i, int bf) {
  return bf ? b2f(((const u16*)p)[i]) : ((const float*)p)[i];
}
// async global->LDS, 16 bytes/lane. LDS dest = base + lane*16 (HW); global addr per-lane.
__device__ __forceinline__ void ld16(const u16* g, u16* l) {
  __builtin_amdgcn_global_load_lds((const __attribute__((address_space(1))) void*)g,
                                   (__attribute__((address_space(3))) void*)l, 16, 0, 0);
}
// unpack 8 u16 (as uint4) -> 8 floats
__device__ __forceinline__ void unpk8(uint4 p, float* o) {
  o[0] = b2f((u16)(p.x & 0xFFFF)); o[1] = b2f((u16)(p.x >> 16));
  o[2] = b2f((u16)(p.y & 0xFFFF)); o[3] = b2f((u16)(p.y >> 16));
  o[4] = b2f((u16)(p.z & 0xFFFF)); o[5] = b2f((u16)(p.z >> 16));
  o[6] = b2f((u16)(p.w & 0xFFFF)); o[7] = b2f((u16)(p.w >> 16));
}
// exact-enough GELU: erf via Abramowitz-Stegun 7.1.26 (|err| <= 1.5e-7) + fast exp.
// ~15 VALU instrs vs ~35 for __ocml_erf_f32.
__device__ __forceinline__ float fast_gelu(float v) {
  float z = fabsf(v) * 0.70710678118654752f;
  float t = 1.0f / (1.0f + 0.3275911f * z);
  float p = t * (0.254829592f +
           t * (-0.284496736f +
           t * (1.421413741f +
           t * (-1.453152027f +
           t * 1.061405429f))));
  float e = __expf(-z * z);
  float er = 1.0f - p * e;             // erf(|z|)
  float s = copysignf(er, v);          // erf(z)
  return 0.5f * v * (1.0f + s);
}

// ---------------- dtype detection ----------------
__global__ void k_detect(const void* __restrict__ g, int* __restrict__ flag) {
  *flag = (((const u16*)g)[0] == 0x3F80u) ? 1 : 0;
}

// ---------------- input x -> f32 / f32 -> out ----------------
__global__ __launch_bounds__(256) void k_x2f(const void* __restrict__ in, float* __restrict__ out,
                                             int n, const int* __restrict__ dt) {
  int bf = *dt;
  int i = blockIdx.x * 256 + threadIdx.x;
  if (i < n) out[i] = ldin(in, i, bf);
}
__global__ __launch_bounds__(256) void k_store(const float* __restrict__ in, void* __restrict__ out,
                                               int n, const int* __restrict__ dt) {
  int bf = *dt;
  int i = blockIdx.x * 256 + threadIdx.x;
  if (i < n) {
    if (bf) ((u16*)out)[i] = f2b(in[i]);
    else ((float*)out)[i] = in[i];
  }
}

// ---------------- weight repack (LDS-tiled, coalesced, batched) ----------------
__device__ __forceinline__ void repack_tile(const void* W, long w_off, u16* R, int N,
                                            int n16tot, int j_off, int kb, int jb, int bf) {
  int t = threadIdx.x;
  __shared__ float tile[32][65];
  int r0 = t >> 6;
  int c = t & 63;
#pragma unroll
  for (int i = 0; i < 8; ++i) {
    int rr = i * 4 + r0;
    tile[rr][c] = ldin(W, w_off + (long)(kb * 32 + rr) * N + jb * 64 + c, bf);
  }
  __syncthreads();
  int lane = t & 63, w = t >> 6;
  alignas(16) u16 tmp[8];
#pragma unroll
  for (int r = 0; r < 8; ++r) tmp[r] = f2b(tile[(lane >> 4) * 8 + r][w * 16 + (lane & 15)]);
  long oidx = (((long)kb * n16tot + j_off + jb * 4 + w) * 64 + lane) * 8;
  *(uint4*)(R + oidx) = *(const uint4*)tmp;
}
// all 512x512 weights: grid (16,8,16); z = layer*4 + type(0=q,1=k,2=v,3=o)
__global__ __launch_bounds__(256) void k_repackQ(const void* wq, const void* wk,
                                                 const void* wv, const void* wo,
                                                 u16* WR, const int* __restrict__ dt) {
  int bf = *dt;
  int z = blockIdx.z, layer = z >> 2, type = z & 3;
  const void* W = (type == 0) ? wq : (type == 1) ? wk : (type == 2) ? wv : wo;
  u16* R = WR + (long)layer * LSTRIDE + (type < 3 ? 0 : 786432);
  int n16tot = (type < 3) ? 96 : 32;
  int j_off = (type < 3) ? type * 32 : 0;
  repack_tile(W, (long)layer * 262144, R, 512, n16tot, j_off, blockIdx.x, blockIdx.y, bf);
}
// w1: grid (16,32,4)
__global__ __launch_bounds__(256) void k_repackF1(const void* w1, u16* WR, const int* __restrict__ dt) {
  int bf = *dt;
  repack_tile(w1, (long)blockIdx.z * 1048576, WR + (long)blockIdx.z * LSTRIDE + 1048576,
              2048, 128, 0, blockIdx.x, blockIdx.y, bf);
}
// w2: grid (64,8,4)
__global__ __launch_bounds__(256) void k_repackF2(const void* w2, u16* WR, const int* __restrict__ dt) {
  int bf = *dt;
  repack_tile(w2, (long)blockIdx.z * 1048576, WR + (long)blockIdx.z * LSTRIDE + 2097152,
              512, 32, 0, blockIdx.x, blockIdx.y, bf);
}

// ---------------- layernorm (f32 in, bf16 out) ----------------
__global__ __launch_bounds__(256) void k_ln(const float* __restrict__ x,
                                            const void* __restrict__ g, const void* __restrict__ b,
                                            long gb_off, u16* __restrict__ out,
                                            const int* __restrict__ dt) {
  int bf = *dt;
  int row = blockIdx.x;
  int t = threadIdx.x;
  const float* xr = x + (size_t)row * DIM;
  float v0 = xr[t], v1 = xr[t + 256];
  float s = v0 + v1;
  float s2 = v0 * v0 + v1 * v1;
#pragma unroll
  for (int off = 32; off > 0; off >>= 1) {
    s += __shfl_down(s, off);
    s2 += __shfl_down(s2, off);
  }
  __shared__ float red[8];
  int lane = t & 63, w = t >> 6;
  if (lane == 0) { red[w] = s; red[4 + w] = s2; }
  __syncthreads();
  float ts = red[0] + red[1] + red[2] + red[3];
  float ts2 = red[4] + red[5] + red[6] + red[7];
  float mean = ts * (1.0f / DIM);
  float var = ts2 * (1.0f / DIM) - mean * mean;
  float rstd = rsqrtf(var + 1e-5f);
  u16* orow = out + (size_t)row * DIM;
  orow[t] = f2b((v0 - mean) * rstd * ldin(g, gb_off + t, bf) + ldin(b, gb_off + t, bf));
  orow[t + 256] = f2b((v1 - mean) * rstd * ldin(g, gb_off + t + 256, bf) + ldin(b, gb_off + t + 256, bf));
}

// ---------------- MFMA GEMM v3 (kept for N=512 GEMMs: WO, W2) ----------------
// C[M,N] = A[M,K] @ W[K,N] (+bias,+gelu,+res). A bf16 row-major, BR repacked fragment-order.
// block 256 = 4 waves in 2(m)x2(n); wave = 64 rows x NJ*16 cols; block tile = 128 x NJ*32.
template <int NJ, bool HAS_BIAS, bool DO_GELU, bool HAS_RES, bool OUT_F32>
__global__ __launch_bounds__(256) void k_gemm3(const u16* __restrict__ A, const u16* __restrict__ BR,
                                               const void* bias, long bias_off,
                                               const float* res, void* outp,
                                               int M, int N, int K, const int* dtflag) {
  int lane = threadIdx.x & 63;
  int wid = threadIdx.x >> 6;
  int wm = wid & 1, wn = wid >> 1;
  int m0 = blockIdx.x * 128;
  int n0 = blockIdx.y * (NJ * 32);
  int n16 = N >> 4;
  int n016 = n0 >> 4;

  constexpr int BUFB = (8 + 2 * NJ) * 1024;  // bytes per staging buffer
  __shared__ alignas(16) char smem[2 * BUFB];

  floatx4 acc[4][NJ];
#pragma unroll
  for (int mi = 0; mi < 4; ++mi)
#pragma unroll
    for (int j = 0; j < NJ; ++j)
#pragma unroll
      for (int r = 0; r < 4; ++r) acc[mi][j][r] = 0.0f;

  // A gather: lane l covers row m0 + wid*32 + (l&15) (+16 for 2nd group), k-chunk (l>>4)*8
  const u16* Ag = A + ((size_t)(m0 + wid * 32 + (lane & 15)) * K + ((lane >> 4) * 8));
  int nKB = K >> 5;

  auto stage = [&](int kb, int b) {
    u16* aL = (u16*)(smem + b * BUFB);
    u16* bL = aL + 4096;
    ld16(Ag + kb * 32, aL + (wid * 2) * 512);
    ld16(Ag + (size_t)16 * K + kb * 32, aL + (wid * 2 + 1) * 512);
#pragma unroll
    for (int s = 0; s < NJ / 2; ++s) {
      int jg = wid * (NJ / 2) + s;
      ld16(BR + (((size_t)kb * n16 + n016 + jg) * 64 + lane) * 8, bL + jg * 512);
    }
  };

  stage(0, 0);
  for (int kb = 0; kb < nKB; ++kb) {
    __syncthreads();  // compiler drains vmcnt before barrier: stage(kb) complete, prev reads done
    if (kb + 1 < nKB) stage(kb + 1, (kb + 1) & 1);
    const u16* aL = (const u16*)(smem + (kb & 1) * BUFB);
    const u16* bL = aL + 4096;
    bf16x8 afr[4], bfr[NJ];
#pragma unroll
    for (int mi = 0; mi < 4; ++mi)
      afr[mi] = *(const bf16x8*)(aL + ((wm * 4 + mi) * 64 + lane) * 8);
#pragma unroll
    for (int j = 0; j < NJ; ++j)
      bfr[j] = *(const bf16x8*)(bL + ((wn * NJ + j) * 64 + lane) * 8);
#pragma unroll
    for (int mi = 0; mi < 4; ++mi)
#pragma unroll
      for (int j = 0; j < NJ; ++j)
        acc[mi][j] = __builtin_amdgcn_mfma_f32_16x16x32_bf16(afr[mi], bfr[j], acc[mi][j], 0, 0, 0);
  }

  // ---- epilogue: per-wave LDS transpose -> coalesced vector stores ----
  __syncthreads();  // staging LDS now reusable
  constexpr int EPS = 84;  // f32 stride per row (2-way banks on write, cheap on read)
  float* ep = (float*)smem + wid * (16 * EPS);
  constexpr int C = NJ * 16;
  int dtv = HAS_BIAS ? *dtflag : 0;
  int nW = n0 + wn * C;
  int mWbase = m0 + wm * 64;

#pragma unroll
  for (int mi = 0; mi < 4; ++mi) {
    // write acc chunk (16 rows x C cols) into ep; apply bias+gelu here (col-indexed)
#pragma unroll
    for (int j = 0; j < NJ; ++j) {
      float bv = HAS_BIAS ? ldin(bias, bias_off + nW + j * 16 + (lane & 15), dtv) : 0.0f;
#pragma unroll
      for (int r = 0; r < 4; ++r) {
        float v = acc[mi][j][r] + bv;
        if (DO_GELU) v = fast_gelu(v);
        ep[((lane >> 4) * 4 + r) * EPS + j * 16 + (lane & 15)] = v;
      }
    }
    __builtin_amdgcn_s_waitcnt(0);  // lgkm drain (wave-private region, no barrier needed)
    if (OUT_F32) {
      constexpr int LPR = C / 4;       // lanes per row (4 f32 each)
      constexpr int RPP = 64 / LPR;    // rows per pass
      constexpr int NP = 16 / RPP;
#pragma unroll
      for (int p = 0; p < NP; ++p) {
        int row = p * RPP + lane / LPR;
        int cb = (lane % LPR) * 4;
        float4 v = *(const float4*)&ep[row * EPS + cb];
        size_t gi = (size_t)(mWbase + mi * 16 + row) * N + nW + cb;
        if (HAS_RES) {
          float4 rv = *(const float4*)&res[gi];
          v.x += rv.x; v.y += rv.y; v.z += rv.z; v.w += rv.w;
        }
        *(float4*)&((float*)outp)[gi] = v;
      }
    } else {
      constexpr int LPR = C / 8;       // lanes per row (8 bf16 each)
      constexpr int RPP = 64 / LPR;
      constexpr int NP = 16 / RPP;
#pragma unroll
      for (int p = 0; p < NP; ++p) {
        int row = p * RPP + lane / LPR;
        int cb = (lane % LPR) * 8;
        const float* er = &ep[row * EPS + cb];
        uint4 pk;
        pk.x = (unsigned)f2b(er[0]) | ((unsigned)f2b(er[1]) << 16);
        pk.y = (unsigned)f2b(er[2]) | ((unsigned)f2b(er[3]) << 16);
        pk.z = (unsigned)f2b(er[4]) | ((unsigned)f2b(er[5]) << 16);
        pk.w = (unsigned)f2b(er[6]) | ((unsigned)f2b(er[7]) << 16);
        size_t gi = (size_t)(mWbase + mi * 16 + row) * N + nW + cb;
        *(uint4*)&((u16*)outp)[gi] = pk;
      }
    }
    __builtin_amdgcn_s_waitcnt(0);  // reads done before next chunk overwrites ep
  }
}

// ---------------- MFMA GEMM v4: 256x256 8-phase counted-vmcnt pipeline ----------------
// For the large-N GEMMs (QKV N=1536, W1 N=2048). Derived from the verified 8-phase
// template (T3+T4 counted vmcnt, T5 setprio), but keeps this kernel family's
// fragment-order LDS trick (per-lane-gathered global_load_lds) => conflict-free
// ds_read_b128 with NO swizzle.
//
// Geometry: block 512 thr = 8 waves (2m x 4n); tile 256x256; BK=64 (K-tile);
// per-wave out 128x64 = 8 mfrag x 4 nfrag; 16 MFMA per phase, 4 phases per K-tile:
//   p0:(kk0,mh0) p1:(kk0,mh1) p2:(kk1,mh0) p3:(kk1,mh1)
// LDS: 2 bufs x (A 32KB + B 32KB) = 128 KiB. buf[c&1] holds K-tile c.
// Fragment-order layout: A block (kk,g) g=row-group(16 rows) at (kk*16+g)*1KB;
//                        B block (kk,j) j=col-group(16)      at (kk*16+j)*1KB.
//
// Race-free staging with 2 buffers (all stages 2 loads/wave except A = 4):
//   p0: stage B(c+1,kk0) -> idle buf      (that buf's reads finished at iter c-1 p3)
//   p1: stage B(c+1,kk1) -> idle buf
//   p3: lgkmcnt(0); barrier  => ALL waves' ds_reads of live buf complete
//       stage A(c+2) -> live buf A region (safe: A fully read)
//       MFMA; vmcnt(4) (leave only the 4 A(c+2) loads in flight); barrier
// Boundary invariant entering iter c: K-tile c fully landed, A(c+1) in flight.
template <bool HAS_BIAS, bool DO_GELU>
__global__ __launch_bounds__(512, 2) void k_gemm8(const u16* __restrict__ A, const u16* __restrict__ BR,
                                                  const void* bias, long bias_off,
                                                  u16* __restrict__ outp,
                                                  int N, int K, const int* dtflag) {
  int lane = threadIdx.x & 63;
  int w = threadIdx.x >> 6;       // wave 0..7
  int wm = w >> 2, wn = w & 3;    // 2 x 4
  int m0 = blockIdx.x * 256;
  int n0 = blockIdx.y * 256;
  int n16 = N >> 4;
  int n016 = n0 >> 4;
  int NKT = K >> 6;               // K-tiles of 64

  __shared__ alignas(16) u16 smem8[65536];  // 128 KiB

  // per-thread global gather bases
  const u16* Ag = A + (size_t)(m0 + w * 16 + (lane & 15)) * K + ((lane >> 4) * 8);
  const u16* Bg = BR + ((size_t)(n016 + w)) * 512 + lane * 8;

  // stage full A of K-tile kt (rows m0..m0+255, k kt*64..+63): 4 loads/thread
  auto stA = [&](int kt, int buf) {
    u16* dst = smem8 + buf * 32768;
    const u16* s = Ag + (size_t)kt * 64;
    ld16(s,                        dst + (0 * 16 + 0 + w) * 512);   // kk0, g=w
    ld16(s + 32,                   dst + (1 * 16 + 0 + w) * 512);   // kk1, g=w
    ld16(s + (size_t)128 * K,      dst + (0 * 16 + 8 + w) * 512);   // kk0, g=8+w
    ld16(s + (size_t)128 * K + 32, dst + (1 * 16 + 8 + w) * 512);   // kk1, g=8+w
  };
  // stage one B kk-half of K-tile kt: 2 loads/thread (j=w, j=8+w)
  auto stB = [&](int kt, int kk, int buf) {
    u16* dst = smem8 + buf * 32768 + 16384 + kk * 16 * 512;
    const u16* s = Bg + ((size_t)(kt * 2 + kk) * n16) * 512;
    ld16(s,           dst + (0 + w) * 512);
    ld16(s + 8 * 512, dst + (8 + w) * 512);
  };

  floatx4 acc[8][4];
#pragma unroll
  for (int mi = 0; mi < 8; ++mi)
#pragma unroll
    for (int j = 0; j < 4; ++j)
#pragma unroll
      for (int r = 0; r < 4; ++r) acc[mi][j][r] = 0.0f;

  // ---- prologue: K0 complete + A(K1) in flight ----
  stA(0, 0);
  stB(0, 0, 0);
  stB(0, 1, 0);
  stA(1, 1);
  asm volatile("s_waitcnt vmcnt(4)" ::: "memory");
  __builtin_amdgcn_s_barrier();

  for (int c = 0; c < NKT; ++c) {
    int buf = c & 1;
    const u16* aL = smem8 + buf * 32768;
    const u16* bL = aL + 16384;

    bf16x8 aA[4], aB[4], aC[4], aD[4], bA[4], bB[4];

    // ---- phase 0: (kk0, mh0) ----
#pragma unroll
    for (int i = 0; i < 4; ++i)
      aA[i] = *(const bf16x8*)(aL + ((0 * 16 + wm * 8 + i) * 64 + lane) * 8);
#pragma unroll
    for (int i = 0; i < 4; ++i)
      bA[i] = *(const bf16x8*)(bL + ((0 * 16 + wn * 4 + i) * 64 + lane) * 8);
#pragma unroll
    for (int i = 0; i < 4; ++i)
      aB[i] = *(const bf16x8*)(aL + ((1 * 16 + wm * 8 + i) * 64 + lane) * 8);  // kk1,mh0 prefetch
    if (c + 1 < NKT) stB(c + 1, 0, buf ^ 1);
    __builtin_amdgcn_s_barrier();
    __builtin_amdgcn_s_setprio(1);
#pragma unroll
    for (int mi = 0; mi < 4; ++mi)
#pragma unroll
      for (int j = 0; j < 4; ++j)
        acc[mi][j] = __builtin_amdgcn_mfma_f32_16x16x32_bf16(aA[mi], bA[j], acc[mi][j], 0, 0, 0);
    __builtin_amdgcn_s_setprio(0);
    __builtin_amdgcn_s_barrier();

    // ---- phase 1: (kk0, mh1) ----
#pragma unroll
    for (int i = 0; i < 4; ++i)
      aC[i] = *(const bf16x8*)(aL + ((0 * 16 + wm * 8 + 4 + i) * 64 + lane) * 8);
#pragma unroll
    for (int i = 0; i < 4; ++i)
      bB[i] = *(const bf16x8*)(bL + ((1 * 16 + wn * 4 + i) * 64 + lane) * 8);  // kk1 prefetch
    if (c + 1 < NKT) stB(c + 1, 1, buf ^ 1);
    __builtin_amdgcn_s_barrier();
    __builtin_amdgcn_s_setprio(1);
#pragma unroll
    for (int mi = 0; mi < 4; ++mi)
#pragma unroll
      for (int j = 0; j < 4; ++j)
        acc[4 + mi][j] = __builtin_amdgcn_mfma_f32_16x16x32_bf16(aC[mi], bA[j], acc[4 + mi][j], 0, 0, 0);
    __builtin_amdgcn_s_setprio(0);
    __builtin_amdgcn_s_barrier();

    // ---- phase 2: (kk1, mh0) ----
#pragma unroll
    for (int i = 0; i < 4; ++i)
      aD[i] = *(const bf16x8*)(aL + ((1 * 16 + wm * 8 + 4 + i) * 64 + lane) * 8);  // kk1,mh1
    __builtin_amdgcn_s_barrier();
    __builtin_amdgcn_s_setprio(1);
#pragma unroll
    for (int mi = 0; mi < 4; ++mi)
#pragma unroll
      for (int j = 0; j < 4; ++j)
        acc[mi][j] = __builtin_amdgcn_mfma_f32_16x16x32_bf16(aB[mi], bB[j], acc[mi][j], 0, 0, 0);
    __builtin_amdgcn_s_setprio(0);
    __builtin_amdgcn_s_barrier();

    // ---- phase 3: (kk1, mh1) + A(c+2) stage into live buf + counted boundary ----
    asm volatile("s_waitcnt lgkmcnt(0)" ::: "memory");
    __builtin_amdgcn_sched_barrier(0);
    __builtin_amdgcn_s_barrier();   // all waves' reads of live buf complete
    if (c + 2 < NKT) stA(c + 2, buf);
    __builtin_amdgcn_s_setprio(1);
#pragma unroll
    for (int mi = 0; mi < 4; ++mi)
#pragma unroll
      for (int j = 0; j < 4; ++j)
        acc[4 + mi][j] = __builtin_amdgcn_mfma_f32_16x16x32_bf16(aD[mi], bB[j], acc[4 + mi][j], 0, 0, 0);
    __builtin_amdgcn_s_setprio(0);
    if (c + 2 < NKT) {
      asm volatile("s_waitcnt vmcnt(4)" ::: "memory");  // leave only A(c+2) in flight
    } else {
      asm volatile("s_waitcnt vmcnt(0)" ::: "memory");  // tail drain
    }
    __builtin_amdgcn_s_barrier();
  }

  // ---- epilogue: per-wave LDS transpose -> coalesced bf16 stores ----
  constexpr int EPS = 68;  // f32 stride per row
  float* ep = (float*)smem8 + w * (16 * EPS);
  int dtv = HAS_BIAS ? *dtflag : 0;
  int nW = n0 + wn * 64;
  int mW = m0 + wm * 128;

#pragma unroll
  for (int mf = 0; mf < 8; ++mf) {
#pragma unroll
    for (int j = 0; j < 4; ++j) {
      float bv = HAS_BIAS ? ldin(bias, bias_off + nW + j * 16 + (lane & 15), dtv) : 0.0f;
#pragma unroll
      for (int r = 0; r < 4; ++r) {
        float v = acc[mf][j][r] + bv;
        if (DO_GELU) v = fast_gelu(v);
        ep[((lane >> 4) * 4 + r) * EPS + j * 16 + (lane & 15)] = v;
      }
    }
    asm volatile("s_waitcnt lgkmcnt(0)" ::: "memory");
    // 16 rows x 64 bf16 cols: 8 lanes/row, 8 rows/pass, 2 passes
#pragma unroll
    for (int p = 0; p < 2; ++p) {
      int row = p * 8 + (lane >> 3);
      int cb = (lane & 7) * 8;
      const float* er = &ep[row * EPS + cb];
      uint4 pk;
      pk.x = (unsigned)f2b(er[0]) | ((unsigned)f2b(er[1]) << 16);
      pk.y = (unsigned)f2b(er[2]) | ((unsigned)f2b(er[3]) << 16);
      pk.z = (unsigned)f2b(er[4]) | ((unsigned)f2b(er[5]) << 16);
      pk.w = (unsigned)f2b(er[6]) | ((unsigned)f2b(er[7]) << 16);
      size_t gi = (size_t)(mW + mf * 16 + row) * N + nW + cb;
      *(uint4*)&outp[gi] = pk;
    }
    asm volatile("s_waitcnt lgkmcnt(0)" ::: "memory");
  }
}

// ---------------- attention phase A: per-bucket exp(k)^T v and key sums ----------------
// grid 1024 = bh*64 + u ; block 256. thread t: d = t>>2, e-slice s = t&3 (16 e's).
__global__ __launch_bounds__(256) void k_attnA(const u16* __restrict__ qkv,
                                               float* __restrict__ Ksum, float* __restrict__ KV) {
  int u = blockIdx.x & 63;
  int bh = blockIdx.x >> 6;
  int head = bh & 7, batch = bh >> 3;
  int t = threadIdx.x;
  int pr = t >> 2, s = t & 3;
  __shared__ float kex[64][68];
  __shared__ float vv[64][68];
  const u16* base = qkv + (size_t)(batch * SEQ + u * 64 + pr) * QKVW + head * DH;
  uint4 kp0 = *(const uint4*)(base + 512 + s * 16);
  uint4 kp1 = *(const uint4*)(base + 512 + s * 16 + 8);
  uint4 vp0 = *(const uint4*)(base + 1024 + s * 16);
  uint4 vp1 = *(const uint4*)(base + 1024 + s * 16 + 8);
  float kf[16], vf[16];
  unpk8(kp0, kf); unpk8(kp1, kf + 8);
  unpk8(vp0, vf); unpk8(vp1, vf + 8);
#pragma unroll
  for (int i = 0; i < 16; ++i) {
    kex[pr][s * 16 + i] = expf(fminf(kf[i], 30.0f));
    vv[pr][s * 16 + i] = vf[i];
  }
  __syncthreads();
  int d = pr;
  float acc[16];
#pragma unroll
  for (int i = 0; i < 16; ++i) acc[i] = 0.0f;
  float ks = 0.0f;
  for (int p = 0; p < 64; ++p) {
    float kp = kex[p][d];
    ks += kp;
#pragma unroll
    for (int i4 = 0; i4 < 4; ++i4) {
      float4 v4 = *(const float4*)&vv[p][s * 16 + i4 * 4];
      acc[i4 * 4 + 0] += kp * v4.x;
      acc[i4 * 4 + 1] += kp * v4.y;
      acc[i4 * 4 + 2] += kp * v4.z;
      acc[i4 * 4 + 3] += kp * v4.w;
    }
  }
  float* kvout = KV + (size_t)blockIdx.x * 4096 + d * 64 + s * 16;
#pragma unroll
  for (int i4 = 0; i4 < 4; ++i4) {
    float4 o; o.x = acc[i4 * 4]; o.y = acc[i4 * 4 + 1]; o.z = acc[i4 * 4 + 2]; o.w = acc[i4 * 4 + 3];
    *(float4*)(kvout + i4 * 4) = o;
  }
  if (s == 0) Ksum[(size_t)blockIdx.x * 64 + d] = ks;
}

// ---------------- attention phase B: exclusive prefix over buckets ----------------
// grid 1024 = bh*64 + d ; block 64 (thread = e). Coalesced 256B per iter.
__global__ __launch_bounds__(64) void k_scan2(float* __restrict__ Ksum, float* __restrict__ KV) {
  int bh = blockIdx.x >> 6;
  int d = blockIdx.x & 63;
  int e = threadIdx.x;
  float run = 0.0f;
  for (int u = 0; u < 64; ++u) {
    float* p = KV + ((size_t)(bh * 64 + u)) * 4096 + d * 64 + e;
    float c = *p;
    *p = run;
    run += c;
  }
  if (d == 0) {
    float r = 0.0f;
    float* kp = Ksum + (size_t)bh * 4096 + e;
    for (int u = 0; u < 64; ++u) {
      float c = kp[u * 64];
      kp[u * 64] = r;
      r += c;
    }
  }
}

// ---------------- attention phase C: softmax(q), D, output ----------------
// grid 1024 ; block 256. thread t: pos = t>>2, e-slice s = t&3.
__global__ __launch_bounds__(256) void k_attnC(const u16* __restrict__ qkv, const float* __restrict__ Ksum,
                                               const float* __restrict__ KV, u16* __restrict__ att) {
  int u = blockIdx.x & 63;
  int bh = blockIdx.x >> 6;
  int head = bh & 7, batch = bh >> 3;
  int t = threadIdx.x;
  int pos = t >> 2, s = t & 3;
  __shared__ float Cm[64][68];
  __shared__ float qs[64][68];
  __shared__ float S[64];
  // load context (this thread's (d=pos, e-slice s) piece)
  const float* kvb = KV + (size_t)blockIdx.x * 4096 + pos * 64 + s * 16;
#pragma unroll
  for (int i4 = 0; i4 < 4; ++i4)
    *(float4*)&Cm[pos][s * 16 + i4 * 4] = *(const float4*)(kvb + i4 * 4);
  if (t < 64) S[t] = Ksum[(size_t)blockIdx.x * 64 + t];
  // softmax(q) for (pos, slice s) with 4-lane team reductions
  size_t grow = (size_t)(batch * SEQ + u * 64 + pos) * QKVW + head * DH;
  uint4 q0 = *(const uint4*)(qkv + grow + s * 16);
  uint4 q1 = *(const uint4*)(qkv + grow + s * 16 + 8);
  float q[16];
  unpk8(q0, q); unpk8(q1, q + 8);
  float mx = q[0];
#pragma unroll
  for (int i = 1; i < 16; ++i) mx = fmaxf(mx, q[i]);
  mx = fmaxf(mx, __shfl_xor(mx, 1));
  mx = fmaxf(mx, __shfl_xor(mx, 2));
  float sum = 0.0f;
#pragma unroll
  for (int i = 0; i < 16; ++i) { q[i] = expf(q[i] - mx); sum += q[i]; }
  sum += __shfl_xor(sum, 1);
  sum += __shfl_xor(sum, 2);
  float scale = 0.125f / sum;  // * e^-0.5 with e=64
  __syncthreads();  // S ready
  float Dp = 0.0f;
#pragma unroll
  for (int i = 0; i < 16; ++i) { q[i] *= scale; Dp += q[i] * S[s * 16 + i]; }
  Dp += __shfl_xor(Dp, 1);
  Dp += __shfl_xor(Dp, 2);
  float Dinv = 1.0f / fmaxf(Dp, 1e-3f);
#pragma unroll
  for (int i = 0; i < 16; ++i) qs[pos][s * 16 + i] = q[i];
  __syncthreads();  // Cm + qs ready
  float o[16];
#pragma unroll
  for (int i = 0; i < 16; ++i) o[i] = 0.0f;
  for (int d = 0; d < 64; ++d) {
    float qd = qs[pos][d];
#pragma unroll
    for (int i4 = 0; i4 < 4; ++i4) {
      float4 c4 = *(const float4*)&Cm[d][s * 16 + i4 * 4];
      o[i4 * 4 + 0] += qd * c4.x;
      o[i4 * 4 + 1] += qd * c4.y;
      o[i4 * 4 + 2] += qd * c4.z;
      o[i4 * 4 + 3] += qd * c4.w;
    }
  }
  u16* orow = att + (size_t)(batch * SEQ + u * 64 + pos) * DIM + head * DH + s * 16;
  uint4 pk0, pk1;
  pk0.x = (unsigned)f2b(o[0] * Dinv) | ((unsigned)f2b(o[1] * Dinv) << 16);
  pk0.y = (unsigned)f2b(o[2] * Dinv) | ((unsigned)f2b(o[3] * Dinv) << 16);
  pk0.z = (unsigned)f2b(o[4] * Dinv) | ((unsigned)f2b(o[5] * Dinv) << 16);
  pk0.w = (unsigned)f2b(o[6] * Dinv) | ((unsigned)f2b(o[7] * Dinv) << 16);
  pk1.x = (unsigned)f2b(o[8] * Dinv) | ((unsigned)f2b(o[9] * Dinv) << 16);
  pk1.y = (unsigned)f2b(o[10] * Dinv) | ((unsigned)f2b(o[11] * Dinv) << 16);
  pk1.z = (unsigned)f2b(o[12] * Dinv) | ((unsigned)f2b(o[13] * Dinv) << 16);
  pk1.w = (unsigned)f2b(o[14] * Dinv) | ((unsigned)f2b(o[15] * Dinv) << 16);
  *(uint4*)orow = pk0;
  *(uint4*)(orow + 8) = pk1;
}

// ---------------- host orchestration ----------------
extern "C" void kernel_launch(void* const* d_in, const int* in_sizes, int n_in,
                              void* d_out, int out_size, void* d_ws, size_t ws_size,
                              hipStream_t stream) {
  (void)in_sizes; (void)n_in; (void)out_size; (void)ws_size;
  const void* x_in = d_in[0];
  const void* ln1_g = d_in[1];
  const void* ln1_b = d_in[2];
  const void* wq = d_in[3];
  const void* wk = d_in[4];
  const void* wv = d_in[5];
  const void* wo = d_in[6];
  const void* bo = d_in[7];
  const void* ln2_g = d_in[8];
  const void* ln2_b = d_in[9];
  const void* w1 = d_in[10];
  const void* b1 = d_in[11];
  const void* w2 = d_in[12];
  const void* b2 = d_in[13];

  char* ws = (char*)d_ws;
  float* xf = (float*)(ws);              // 16 MiB f32 residual
  u16* h = (u16*)(ws + 16777216);        // 8 MiB bf16
  u16* region = (u16*)(ws + 25165824);   // 32 MiB: qkv (24 MiB) / gb (32 MiB)
  float* Ksum = (float*)(ws + 58720256); // 256 KiB
  float* KV = (float*)(ws + 58982400);   // 16 MiB
  u16* WR = (u16*)(ws + 75759616);       // 24 MiB repacked weights
  int* dt = (int*)(ws + 100925440);      // dtype flag
  u16* qkv = region;
  u16* gb = region;

  auto WqkvR = [&](int i) { return WR + (size_t)i * LSTRIDE + 0; };
  auto WoR   = [&](int i) { return WR + (size_t)i * LSTRIDE + 786432; };
  auto W1R   = [&](int i) { return WR + (size_t)i * LSTRIDE + 1048576; };
  auto W2R   = [&](int i) { return WR + (size_t)i * LSTRIDE + 2097152; };

  k_detect<<<dim3(1), dim3(1), 0, stream>>>(ln1_g, dt);

  const int nx = ROWS * DIM;
  k_x2f<<<dim3((nx + 255) / 256), dim3(256), 0, stream>>>(x_in, xf, nx, dt);

  k_repackQ<<<dim3(16, 8, 16), dim3(256), 0, stream>>>(wq, wk, wv, wo, WR, dt);
  k_repackF1<<<dim3(16, 32, 4), dim3(256), 0, stream>>>(w1, WR, dt);
  k_repackF2<<<dim3(64, 8, 4), dim3(256), 0, stream>>>(w2, WR, dt);

  for (int i = 0; i < 4; ++i) {
    // PreNorm(attn)
    k_ln<<<dim3(ROWS), dim3(256), 0, stream>>>(xf, ln1_g, ln1_b, (long)i * DIM, h, dt);
    // fused QKV gemm: [8192,512] @ [512,1536] — 8-phase 256x256 pipeline
    k_gemm8<false, false><<<dim3(32, 6), dim3(512), 0, stream>>>(
        h, WqkvR(i), nullptr, 0, qkv, QKVW, DIM, dt);
    k_attnA<<<dim3(1024), dim3(256), 0, stream>>>(qkv, Ksum, KV);
    k_scan2<<<dim3(1024), dim3(64), 0, stream>>>(Ksum, KV);
    k_attnC<<<dim3(1024), dim3(256), 0, stream>>>(qkv, Ksum, KV, h);  // att -> h
    // x += att @ wo + bo  (N=512: stays on 128-tile kernel)
    k_gemm3<2, true, false, true, true><<<dim3(64, 8), dim3(256), 0, stream>>>(
        h, WoR(i), bo, (long)i * DIM, xf, xf, ROWS, DIM, DIM, dt);
    // PreNorm(FF)
    k_ln<<<dim3(ROWS), dim3(256), 0, stream>>>(xf, ln2_g, ln2_b, (long)i * DIM, h, dt);
    // FF up: [8192,512] @ [512,2048] + bias + gelu — 8-phase 256x256 pipeline
    k_gemm8<true, true><<<dim3(32, 8), dim3(512), 0, stream>>>(
        h, W1R(i), b1, (long)i * FFDIM, gb, FFDIM, DIM, dt);
    // FF down: [8192,2048] @ [2048,512] + bias + residual (N=512: stays on 128-tile)
    k_gemm3<2, true, false, true, true><<<dim3(64, 8), dim3(256), 0, stream>>>(
        gb, W2R(i), b2, (long)i * DIM, xf, xf, ROWS, DIM, FFDIM, dt);
  }

  k_store<<<dim3((nx + 255) / 256), dim3(256), 0, stream>>>(xf, d_out, nx, dt);
}

// Round 2
// 872.804 us; speedup vs baseline: 1.0086x; 1.0033x over previous
//
#include <hip/hip_runtime.h>

// ---------------- types / helpers ----------------
typedef unsigned short u16;
typedef __bf16 bf16x8 __attribute__((ext_vector_type(8)));
typedef float floatx4 __attribute__((ext_vector_type(4)));

#define DIM 512
#define HEADS 8
#define DH 64
#define SEQ 4096
#define BATCH 2
#define ROWS (BATCH * SEQ) /* 8192 */
#define FFDIM 2048
#define QKVW 1536 /* fused qkv row width */
#define LSTRIDE 3145728L /* repacked weight elems per layer */

__device__ __forceinline__ float b2f(u16 u) {
  union { float f; unsigned int i; } c; c.i = ((unsigned int)u) << 16; return c.f;
}
__device__ __forceinline__ u16 f2b(float f) {
  union { float f; unsigned int i; } c; c.f = f;
  unsigned int r = c.i + 0x7FFFu + ((c.i >> 16) & 1u);
  return (u16)(r >> 16);
}
__device__ __forceinline__ float ldin(const void* p, long i, int bf) {
  return bf ? b2f(((const u16*)p)[i]) : ((const float*)p)[i];
}
// async global->LDS, 16 bytes/lane. LDS dest = base + lane*16 (HW); global addr per-lane.
__device__ __forceinline__ void ld16(const u16* g, u16* l) {
  __builtin_amdgcn_global_load_lds((const __attribute__((address_space(1))) void*)g,
                                   (__attribute__((address_space(3))) void*)l, 16, 0, 0);
}
// unpack 8 u16 (as uint4) -> 8 floats
__device__ __forceinline__ void unpk8(uint4 p, float* o) {
  o[0] = b2f((u16)(p.x & 0xFFFF)); o[1] = b2f((u16)(p.x >> 16));
  o[2] = b2f((u16)(p.y & 0xFFFF)); o[3] = b2f((u16)(p.y >> 16));
  o[4] = b2f((u16)(p.z & 0xFFFF)); o[5] = b2f((u16)(p.z >> 16));
  o[6] = b2f((u16)(p.w & 0xFFFF)); o[7] = b2f((u16)(p.w >> 16));
}
// exact-enough GELU: erf via Abramowitz-Stegun 7.1.26 (|err| <= 1.5e-7) + fast exp.
__device__ __forceinline__ float fast_gelu(float v) {
  float z = fabsf(v) * 0.70710678118654752f;
  float t = 1.0f / (1.0f + 0.3275911f * z);
  float p = t * (0.254829592f +
           t * (-0.284496736f +
           t * (1.421413741f +
           t * (-1.453152027f +
           t * 1.061405429f))));
  float e = __expf(-z * z);
  float er = 1.0f - p * e;             // erf(|z|)
  float s = copysignf(er, v);          // erf(z)
  return 0.5f * v * (1.0f + s);
}

// ---------------- dtype detection ----------------
__global__ void k_detect(const void* __restrict__ g, int* __restrict__ flag) {
  *flag = (((const u16*)g)[0] == 0x3F80u) ? 1 : 0;
}

// ---------------- input x -> f32 / f32 -> out ----------------
__global__ __launch_bounds__(256) void k_x2f(const void* __restrict__ in, float* __restrict__ out,
                                             int n, const int* __restrict__ dt) {
  int bf = *dt;
  int i = blockIdx.x * 256 + threadIdx.x;
  if (i < n) out[i] = ldin(in, i, bf);
}
__global__ __launch_bounds__(256) void k_store(const float* __restrict__ in, void* __restrict__ out,
                                               int n, const int* __restrict__ dt) {
  int bf = *dt;
  int i = blockIdx.x * 256 + threadIdx.x;
  if (i < n) {
    if (bf) ((u16*)out)[i] = f2b(in[i]);
    else ((float*)out)[i] = in[i];
  }
}

// ---------------- weight repack (LDS-tiled, coalesced, batched) ----------------
__device__ __forceinline__ void repack_tile(const void* W, long w_off, u16* R, int N,
                                            int n16tot, int j_off, int kb, int jb, int bf) {
  int t = threadIdx.x;
  __shared__ float tile[32][65];
  int r0 = t >> 6;
  int c = t & 63;
#pragma unroll
  for (int i = 0; i < 8; ++i) {
    int rr = i * 4 + r0;
    tile[rr][c] = ldin(W, w_off + (long)(kb * 32 + rr) * N + jb * 64 + c, bf);
  }
  __syncthreads();
  int lane = t & 63, w = t >> 6;
  alignas(16) u16 tmp[8];
#pragma unroll
  for (int r = 0; r < 8; ++r) tmp[r] = f2b(tile[(lane >> 4) * 8 + r][w * 16 + (lane & 15)]);
  long oidx = (((long)kb * n16tot + j_off + jb * 4 + w) * 64 + lane) * 8;
  *(uint4*)(R + oidx) = *(const uint4*)tmp;
}
// all 512x512 weights: grid (16,8,16); z = layer*4 + type(0=q,1=k,2=v,3=o)
__global__ __launch_bounds__(256) void k_repackQ(const void* wq, const void* wk,
                                                 const void* wv, const void* wo,
                                                 u16* WR, const int* __restrict__ dt) {
  int bf = *dt;
  int z = blockIdx.z, layer = z >> 2, type = z & 3;
  const void* W = (type == 0) ? wq : (type == 1) ? wk : (type == 2) ? wv : wo;
  u16* R = WR + (long)layer * LSTRIDE + (type < 3 ? 0 : 786432);
  int n16tot = (type < 3) ? 96 : 32;
  int j_off = (type < 3) ? type * 32 : 0;
  repack_tile(W, (long)layer * 262144, R, 512, n16tot, j_off, blockIdx.x, blockIdx.y, bf);
}
// w1: grid (16,32,4)
__global__ __launch_bounds__(256) void k_repackF1(const void* w1, u16* WR, const int* __restrict__ dt) {
  int bf = *dt;
  repack_tile(w1, (long)blockIdx.z * 1048576, WR + (long)blockIdx.z * LSTRIDE + 1048576,
              2048, 128, 0, blockIdx.x, blockIdx.y, bf);
}
// w2: grid (64,8,4)
__global__ __launch_bounds__(256) void k_repackF2(const void* w2, u16* WR, const int* __restrict__ dt) {
  int bf = *dt;
  repack_tile(w2, (long)blockIdx.z * 1048576, WR + (long)blockIdx.z * LSTRIDE + 2097152,
              512, 32, 0, blockIdx.x, blockIdx.y, bf);
}

// ---------------- layernorm (f32 in, bf16 out) ----------------
__global__ __launch_bounds__(256) void k_ln(const float* __restrict__ x,
                                            const void* __restrict__ g, const void* __restrict__ b,
                                            long gb_off, u16* __restrict__ out,
                                            const int* __restrict__ dt) {
  int bf = *dt;
  int row = blockIdx.x;
  int t = threadIdx.x;
  const float* xr = x + (size_t)row * DIM;
  float v0 = xr[t], v1 = xr[t + 256];
  float s = v0 + v1;
  float s2 = v0 * v0 + v1 * v1;
#pragma unroll
  for (int off = 32; off > 0; off >>= 1) {
    s += __shfl_down(s, off);
    s2 += __shfl_down(s2, off);
  }
  __shared__ float red[8];
  int lane = t & 63, w = t >> 6;
  if (lane == 0) { red[w] = s; red[4 + w] = s2; }
  __syncthreads();
  float ts = red[0] + red[1] + red[2] + red[3];
  float ts2 = red[4] + red[5] + red[6] + red[7];
  float mean = ts * (1.0f / DIM);
  float var = ts2 * (1.0f / DIM) - mean * mean;
  float rstd = rsqrtf(var + 1e-5f);
  u16* orow = out + (size_t)row * DIM;
  orow[t] = f2b((v0 - mean) * rstd * ldin(g, gb_off + t, bf) + ldin(b, gb_off + t, bf));
  orow[t + 256] = f2b((v1 - mean) * rstd * ldin(g, gb_off + t + 256, bf) + ldin(b, gb_off + t + 256, bf));
}

// ---------------- MFMA GEMM v3 (kept for N=512 GEMMs: WO, W2) ----------------
template <int NJ, bool HAS_BIAS, bool DO_GELU, bool HAS_RES, bool OUT_F32>
__global__ __launch_bounds__(256) void k_gemm3(const u16* __restrict__ A, const u16* __restrict__ BR,
                                               const void* bias, long bias_off,
                                               const float* res, void* outp,
                                               int M, int N, int K, const int* dtflag) {
  int lane = threadIdx.x & 63;
  int wid = threadIdx.x >> 6;
  int wm = wid & 1, wn = wid >> 1;
  int m0 = blockIdx.x * 128;
  int n0 = blockIdx.y * (NJ * 32);
  int n16 = N >> 4;
  int n016 = n0 >> 4;

  constexpr int BUFB = (8 + 2 * NJ) * 1024;  // bytes per staging buffer
  __shared__ alignas(16) char smem[2 * BUFB];

  floatx4 acc[4][NJ];
#pragma unroll
  for (int mi = 0; mi < 4; ++mi)
#pragma unroll
    for (int j = 0; j < NJ; ++j)
#pragma unroll
      for (int r = 0; r < 4; ++r) acc[mi][j][r] = 0.0f;

  const u16* Ag = A + ((size_t)(m0 + wid * 32 + (lane & 15)) * K + ((lane >> 4) * 8));
  int nKB = K >> 5;

  auto stage = [&](int kb, int b) {
    u16* aL = (u16*)(smem + b * BUFB);
    u16* bL = aL + 4096;
    ld16(Ag + kb * 32, aL + (wid * 2) * 512);
    ld16(Ag + (size_t)16 * K + kb * 32, aL + (wid * 2 + 1) * 512);
#pragma unroll
    for (int s = 0; s < NJ / 2; ++s) {
      int jg = wid * (NJ / 2) + s;
      ld16(BR + (((size_t)kb * n16 + n016 + jg) * 64 + lane) * 8, bL + jg * 512);
    }
  };

  stage(0, 0);
  for (int kb = 0; kb < nKB; ++kb) {
    __syncthreads();
    if (kb + 1 < nKB) stage(kb + 1, (kb + 1) & 1);
    const u16* aL = (const u16*)(smem + (kb & 1) * BUFB);
    const u16* bL = aL + 4096;
    bf16x8 afr[4], bfr[NJ];
#pragma unroll
    for (int mi = 0; mi < 4; ++mi)
      afr[mi] = *(const bf16x8*)(aL + ((wm * 4 + mi) * 64 + lane) * 8);
#pragma unroll
    for (int j = 0; j < NJ; ++j)
      bfr[j] = *(const bf16x8*)(bL + ((wn * NJ + j) * 64 + lane) * 8);
#pragma unroll
    for (int mi = 0; mi < 4; ++mi)
#pragma unroll
      for (int j = 0; j < NJ; ++j)
        acc[mi][j] = __builtin_amdgcn_mfma_f32_16x16x32_bf16(afr[mi], bfr[j], acc[mi][j], 0, 0, 0);
  }

  // ---- epilogue: per-wave LDS transpose -> coalesced vector stores ----
  __syncthreads();
  constexpr int EPS = 84;
  float* ep = (float*)smem + wid * (16 * EPS);
  constexpr int C = NJ * 16;
  int dtv = HAS_BIAS ? *dtflag : 0;
  int nW = n0 + wn * C;
  int mWbase = m0 + wm * 64;

#pragma unroll
  for (int mi = 0; mi < 4; ++mi) {
#pragma unroll
    for (int j = 0; j < NJ; ++j) {
      float bv = HAS_BIAS ? ldin(bias, bias_off + nW + j * 16 + (lane & 15), dtv) : 0.0f;
#pragma unroll
      for (int r = 0; r < 4; ++r) {
        float v = acc[mi][j][r] + bv;
        if (DO_GELU) v = fast_gelu(v);
        ep[((lane >> 4) * 4 + r) * EPS + j * 16 + (lane & 15)] = v;
      }
    }
    __builtin_amdgcn_s_waitcnt(0);
    if (OUT_F32) {
      constexpr int LPR = C / 4;
      constexpr int RPP = 64 / LPR;
      constexpr int NP = 16 / RPP;
#pragma unroll
      for (int p = 0; p < NP; ++p) {
        int row = p * RPP + lane / LPR;
        int cb = (lane % LPR) * 4;
        float4 v = *(const float4*)&ep[row * EPS + cb];
        size_t gi = (size_t)(mWbase + mi * 16 + row) * N + nW + cb;
        if (HAS_RES) {
          float4 rv = *(const float4*)&res[gi];
          v.x += rv.x; v.y += rv.y; v.z += rv.z; v.w += rv.w;
        }
        *(float4*)&((float*)outp)[gi] = v;
      }
    } else {
      constexpr int LPR = C / 8;
      constexpr int RPP = 64 / LPR;
      constexpr int NP = 16 / RPP;
#pragma unroll
      for (int p = 0; p < NP; ++p) {
        int row = p * RPP + lane / LPR;
        int cb = (lane % LPR) * 8;
        const float* er = &ep[row * EPS + cb];
        uint4 pk;
        pk.x = (unsigned)f2b(er[0]) | ((unsigned)f2b(er[1]) << 16);
        pk.y = (unsigned)f2b(er[2]) | ((unsigned)f2b(er[3]) << 16);
        pk.z = (unsigned)f2b(er[4]) | ((unsigned)f2b(er[5]) << 16);
        pk.w = (unsigned)f2b(er[6]) | ((unsigned)f2b(er[7]) << 16);
        size_t gi = (size_t)(mWbase + mi * 16 + row) * N + nW + cb;
        *(uint4*)&((u16*)outp)[gi] = pk;
      }
    }
    __builtin_amdgcn_s_waitcnt(0);
  }
}

// ---------------- MFMA GEMM v4.2: 256x256 4-phase staggered counted-vmcnt pipeline ----
// m201-faithful port. Block 512 thr = 8 waves (2m x 4n); tile 256x256; K-tile 64 (2 kk's).
// Per wave: 128x64 out = acc[8][4]; per phase 16 MFMA (one mh half x one kk).
// LDS: 2 bufs x (A 32KB | B 32KB) = 128 KiB, fragment-order (no swizzle, conflict-free).
//
// Staging: one 2-load half-stage per phase, staggered 5-6 phases ahead of consumption:
//   ph0(c): A_kk1(c+1) -> buf^1     ph1(c): B_kk1(c+1) -> buf^1
//   ph2(c): A_kk0(c+2) -> buf       ph3(c): B_kk0(c+2) -> buf
// (kk0 regions of live buf are dead after ph1; kk1 dead after ph3 -> no W/R overlap.)
// Counted waits (never 0 in steady state), each followed by a barrier so per-wave vmcnt
// becomes a cross-wave guarantee:
//   end ph1: vmcnt(8) -> A_kk1(c),B_kk1(c) landed (4 younger stages in flight)
//   end ph3: vmcnt(8) -> A_kk0(c+1),B_kk0(c+1) landed
// Tail: sources clamped to last tile (dummy stages keep counts uniform); vmcnt(0) after loop.
// Register budget: acc 128 + afr 16 + bfr 16 + addressing ~30 => ~190 VGPR, no spill @ 2 w/EU.
template <bool HAS_BIAS, bool DO_GELU>
__global__ __launch_bounds__(512, 2) void k_gemm8(const u16* __restrict__ A, const u16* __restrict__ BR,
                                                  const void* bias, long bias_off,
                                                  u16* __restrict__ outp,
                                                  int N, int K, const int* dtflag) {
  int lane = threadIdx.x & 63;
  int w = threadIdx.x >> 6;       // wave 0..7
  int wm = w >> 2, wn = w & 3;    // 2 x 4
  int m0 = blockIdx.x * 256;
  int n0 = blockIdx.y * 256;
  int n16 = N >> 4;
  int n016 = n0 >> 4;
  int NKT = K >> 6;               // K-tiles of 64

  __shared__ alignas(16) u16 smem8[65536];  // 128 KiB

  // per-thread global gather bases (fragment-order: lane&15 = row/col, lane>>4 = k-subchunk)
  const u16* Abase = A + (size_t)(m0 + (lane & 15)) * K + ((lane >> 4) * 8);
  const u16* Bbase = BR + (size_t)n016 * 512 + lane * 8;

  // stage A half (kk) of K-tile kt: 2 loads (row-groups g=w, g=8+w)
  auto stA = [&](int kt, int kk, int dbuf) {
    int kb = kt * 2 + kk;
    const u16* s = Abase + (size_t)kb * 32;
    u16* dst = smem8 + dbuf * 32768 + (kk * 16) * 512;
    ld16(s + (size_t)w * 16 * K,       dst + (0 + w) * 512);
    ld16(s + (size_t)(8 + w) * 16 * K, dst + (8 + w) * 512);
  };
  // stage B half (kk) of K-tile kt: 2 loads (col-groups j=w, j=8+w)
  auto stB = [&](int kt, int kk, int dbuf) {
    int kb = kt * 2 + kk;
    const u16* s = Bbase + (size_t)kb * n16 * 512;
    u16* dst = smem8 + dbuf * 32768 + 16384 + (kk * 16) * 512;
    ld16(s + (size_t)w * 512,       dst + (0 + w) * 512);
    ld16(s + (size_t)(8 + w) * 512, dst + (8 + w) * 512);
  };

  floatx4 acc[8][4];
#pragma unroll
  for (int mi = 0; mi < 8; ++mi)
#pragma unroll
    for (int j = 0; j < 4; ++j)
#pragma unroll
      for (int r = 0; r < 4; ++r) acc[mi][j][r] = 0.0f;

  // ---- prologue: stage in consumption order; 12 loads in flight ----
  stA(0, 0, 0); stB(0, 0, 0);
  stA(0, 1, 0); stB(0, 1, 0);
  stA(1, 0, 1); stB(1, 0, 1);
  // oldest 4 (A_kk0(0), B_kk0(0)) guaranteed before first reads:
  asm volatile("s_waitcnt vmcnt(8)" ::: "memory");
  __builtin_amdgcn_s_barrier();

  for (int c = 0; c < NKT; ++c) {
    int buf = c & 1;
    const u16* aL = smem8 + buf * 32768;
    const u16* bL = aL + 16384;
    int kt1 = (c + 1 < NKT) ? c + 1 : NKT - 1;  // clamped source (dummy at tail)
    int kt2 = (c + 2 < NKT) ? c + 2 : NKT - 1;
    bf16x8 afr[4], bfr[4];

    // ---- phase 0: (kk0, mh0) ----
#pragma unroll
    for (int i = 0; i < 4; ++i)
      afr[i] = *(const bf16x8*)(aL + ((0 * 16 + wm * 8 + i) * 64 + lane) * 8);
#pragma unroll
    for (int i = 0; i < 4; ++i)
      bfr[i] = *(const bf16x8*)(bL + ((0 * 16 + wn * 4 + i) * 64 + lane) * 8);
    stA(kt1, 1, buf ^ 1);
    __builtin_amdgcn_s_barrier();
    asm volatile("s_waitcnt lgkmcnt(0)" ::: "memory");
    __builtin_amdgcn_s_setprio(1);
#pragma unroll
    for (int mi = 0; mi < 4; ++mi)
#pragma unroll
      for (int j = 0; j < 4; ++j)
        acc[mi][j] = __builtin_amdgcn_mfma_f32_16x16x32_bf16(afr[mi], bfr[j], acc[mi][j], 0, 0, 0);
    __builtin_amdgcn_s_setprio(0);
    __builtin_amdgcn_s_barrier();

    // ---- phase 1: (kk0, mh1) ----
#pragma unroll
    for (int i = 0; i < 4; ++i)
      afr[i] = *(const bf16x8*)(aL + ((0 * 16 + wm * 8 + 4 + i) * 64 + lane) * 8);
    stB(kt1, 1, buf ^ 1);
    __builtin_amdgcn_s_barrier();
    asm volatile("s_waitcnt lgkmcnt(0)" ::: "memory");
    __builtin_amdgcn_s_setprio(1);
#pragma unroll
    for (int mi = 0; mi < 4; ++mi)
#pragma unroll
      for (int j = 0; j < 4; ++j)
        acc[4 + mi][j] = __builtin_amdgcn_mfma_f32_16x16x32_bf16(afr[mi], bfr[j], acc[4 + mi][j], 0, 0, 0);
    __builtin_amdgcn_s_setprio(0);
    // kk1 halves of tile c (staged 5-6 phases ago) must land; 4 younger stages stay in flight
    asm volatile("s_waitcnt vmcnt(8)" ::: "memory");
    __builtin_amdgcn_s_barrier();

    // ---- phase 2: (kk1, mh0) ----
#pragma unroll
    for (int i = 0; i < 4; ++i)
      afr[i] = *(const bf16x8*)(aL + ((1 * 16 + wm * 8 + i) * 64 + lane) * 8);
#pragma unroll
    for (int i = 0; i < 4; ++i)
      bfr[i] = *(const bf16x8*)(bL + ((1 * 16 + wn * 4 + i) * 64 + lane) * 8);
    stA(kt2, 0, buf);
    __builtin_amdgcn_s_barrier();
    asm volatile("s_waitcnt lgkmcnt(0)" ::: "memory");
    __builtin_amdgcn_s_setprio(1);
#pragma unroll
    for (int mi = 0; mi < 4; ++mi)
#pragma unroll
      for (int j = 0; j < 4; ++j)
        acc[mi][j] = __builtin_amdgcn_mfma_f32_16x16x32_bf16(afr[mi], bfr[j], acc[mi][j], 0, 0, 0);
    __builtin_amdgcn_s_setprio(0);
    __builtin_amdgcn_s_barrier();

    // ---- phase 3: (kk1, mh1) ----
#pragma unroll
    for (int i = 0; i < 4; ++i)
      afr[i] = *(const bf16x8*)(aL + ((1 * 16 + wm * 8 + 4 + i) * 64 + lane) * 8);
    stB(kt2, 0, buf);
    __builtin_amdgcn_s_barrier();
    asm volatile("s_waitcnt lgkmcnt(0)" ::: "memory");
    __builtin_amdgcn_s_setprio(1);
#pragma unroll
    for (int mi = 0; mi < 4; ++mi)
#pragma unroll
      for (int j = 0; j < 4; ++j)
        acc[4 + mi][j] = __builtin_amdgcn_mfma_f32_16x16x32_bf16(afr[mi], bfr[j], acc[4 + mi][j], 0, 0, 0);
    __builtin_amdgcn_s_setprio(0);
    // kk0 halves of tile c+1 must land before next iter's ph0 reads
    asm volatile("s_waitcnt vmcnt(8)" ::: "memory");
    __builtin_amdgcn_s_barrier();
  }

  // drain dummy/tail stages before reusing LDS
  asm volatile("s_waitcnt vmcnt(0)" ::: "memory");
  __builtin_amdgcn_s_barrier();

  // ---- epilogue: per-wave LDS transpose -> coalesced bf16 stores ----
  constexpr int EPS = 68;
  float* ep = (float*)smem8 + w * (16 * EPS);
  int dtv = HAS_BIAS ? *dtflag : 0;
  int nW = n0 + wn * 64;
  int mW = m0 + wm * 128;

#pragma unroll
  for (int mf = 0; mf < 8; ++mf) {
#pragma unroll
    for (int j = 0; j < 4; ++j) {
      float bv = HAS_BIAS ? ldin(bias, bias_off + nW + j * 16 + (lane & 15), dtv) : 0.0f;
#pragma unroll
      for (int r = 0; r < 4; ++r) {
        float v = acc[mf][j][r] + bv;
        if (DO_GELU) v = fast_gelu(v);
        ep[((lane >> 4) * 4 + r) * EPS + j * 16 + (lane & 15)] = v;
      }
    }
    asm volatile("s_waitcnt lgkmcnt(0)" ::: "memory");
#pragma unroll
    for (int p = 0; p < 2; ++p) {
      int row = p * 8 + (lane >> 3);
      int cb = (lane & 7) * 8;
      const float* er = &ep[row * EPS + cb];
      uint4 pk;
      pk.x = (unsigned)f2b(er[0]) | ((unsigned)f2b(er[1]) << 16);
      pk.y = (unsigned)f2b(er[2]) | ((unsigned)f2b(er[3]) << 16);
      pk.z = (unsigned)f2b(er[4]) | ((unsigned)f2b(er[5]) << 16);
      pk.w = (unsigned)f2b(er[6]) | ((unsigned)f2b(er[7]) << 16);
      size_t gi = (size_t)(mW + mf * 16 + row) * N + nW + cb;
      *(uint4*)&outp[gi] = pk;
    }
    asm volatile("s_waitcnt lgkmcnt(0)" ::: "memory");
  }
}

// ---------------- attention phase A: per-bucket exp(k)^T v and key sums ----------------
__global__ __launch_bounds__(256) void k_attnA(const u16* __restrict__ qkv,
                                               float* __restrict__ Ksum, float* __restrict__ KV) {
  int u = blockIdx.x & 63;
  int bh = blockIdx.x >> 6;
  int head = bh & 7, batch = bh >> 3;
  int t = threadIdx.x;
  int pr = t >> 2, s = t & 3;
  __shared__ float kex[64][68];
  __shared__ float vv[64][68];
  const u16* base = qkv + (size_t)(batch * SEQ + u * 64 + pr) * QKVW + head * DH;
  uint4 kp0 = *(const uint4*)(base + 512 + s * 16);
  uint4 kp1 = *(const uint4*)(base + 512 + s * 16 + 8);
  uint4 vp0 = *(const uint4*)(base + 1024 + s * 16);
  uint4 vp1 = *(const uint4*)(base + 1024 + s * 16 + 8);
  float kf[16], vf[16];
  unpk8(kp0, kf); unpk8(kp1, kf + 8);
  unpk8(vp0, vf); unpk8(vp1, vf + 8);
#pragma unroll
  for (int i = 0; i < 16; ++i) {
    kex[pr][s * 16 + i] = expf(fminf(kf[i], 30.0f));
    vv[pr][s * 16 + i] = vf[i];
  }
  __syncthreads();
  int d = pr;
  float acc[16];
#pragma unroll
  for (int i = 0; i < 16; ++i) acc[i] = 0.0f;
  float ks = 0.0f;
  for (int p = 0; p < 64; ++p) {
    float kp = kex[p][d];
    ks += kp;
#pragma unroll
    for (int i4 = 0; i4 < 4; ++i4) {
      float4 v4 = *(const float4*)&vv[p][s * 16 + i4 * 4];
      acc[i4 * 4 + 0] += kp * v4.x;
      acc[i4 * 4 + 1] += kp * v4.y;
      acc[i4 * 4 + 2] += kp * v4.z;
      acc[i4 * 4 + 3] += kp * v4.w;
    }
  }
  float* kvout = KV + (size_t)blockIdx.x * 4096 + d * 64 + s * 16;
#pragma unroll
  for (int i4 = 0; i4 < 4; ++i4) {
    float4 o; o.x = acc[i4 * 4]; o.y = acc[i4 * 4 + 1]; o.z = acc[i4 * 4 + 2]; o.w = acc[i4 * 4 + 3];
    *(float4*)(kvout + i4 * 4) = o;
  }
  if (s == 0) Ksum[(size_t)blockIdx.x * 64 + d] = ks;
}

// ---------------- attention phase B: exclusive prefix over buckets ----------------
__global__ __launch_bounds__(64) void k_scan2(float* __restrict__ Ksum, float* __restrict__ KV) {
  int bh = blockIdx.x >> 6;
  int d = blockIdx.x & 63;
  int e = threadIdx.x;
  float run = 0.0f;
  for (int u = 0; u < 64; ++u) {
    float* p = KV + ((size_t)(bh * 64 + u)) * 4096 + d * 64 + e;
    float c = *p;
    *p = run;
    run += c;
  }
  if (d == 0) {
    float r = 0.0f;
    float* kp = Ksum + (size_t)bh * 4096 + e;
    for (int u = 0; u < 64; ++u) {
      float c = kp[u * 64];
      kp[u * 64] = r;
      r += c;
    }
  }
}

// ---------------- attention phase C: softmax(q), D, output ----------------
__global__ __launch_bounds__(256) void k_attnC(const u16* __restrict__ qkv, const float* __restrict__ Ksum,
                                               const float* __restrict__ KV, u16* __restrict__ att) {
  int u = blockIdx.x & 63;
  int bh = blockIdx.x >> 6;
  int head = bh & 7, batch = bh >> 3;
  int t = threadIdx.x;
  int pos = t >> 2, s = t & 3;
  __shared__ float Cm[64][68];
  __shared__ float qs[64][68];
  __shared__ float S[64];
  const float* kvb = KV + (size_t)blockIdx.x * 4096 + pos * 64 + s * 16;
#pragma unroll
  for (int i4 = 0; i4 < 4; ++i4)
    *(float4*)&Cm[pos][s * 16 + i4 * 4] = *(const float4*)(kvb + i4 * 4);
  if (t < 64) S[t] = Ksum[(size_t)blockIdx.x * 64 + t];
  size_t grow = (size_t)(batch * SEQ + u * 64 + pos) * QKVW + head * DH;
  uint4 q0 = *(const uint4*)(qkv + grow + s * 16);
  uint4 q1 = *(const uint4*)(qkv + grow + s * 16 + 8);
  float q[16];
  unpk8(q0, q); unpk8(q1, q + 8);
  float mx = q[0];
#pragma unroll
  for (int i = 1; i < 16; ++i) mx = fmaxf(mx, q[i]);
  mx = fmaxf(mx, __shfl_xor(mx, 1));
  mx = fmaxf(mx, __shfl_xor(mx, 2));
  float sum = 0.0f;
#pragma unroll
  for (int i = 0; i < 16; ++i) { q[i] = expf(q[i] - mx); sum += q[i]; }
  sum += __shfl_xor(sum, 1);
  sum += __shfl_xor(sum, 2);
  float scale = 0.125f / sum;  // * e^-0.5 with e=64
  __syncthreads();  // S ready
  float Dp = 0.0f;
#pragma unroll
  for (int i = 0; i < 16; ++i) { q[i] *= scale; Dp += q[i] * S[s * 16 + i]; }
  Dp += __shfl_xor(Dp, 1);
  Dp += __shfl_xor(Dp, 2);
  float Dinv = 1.0f / fmaxf(Dp, 1e-3f);
#pragma unroll
  for (int i = 0; i < 16; ++i) qs[pos][s * 16 + i] = q[i];
  __syncthreads();  // Cm + qs ready
  float o[16];
#pragma unroll
  for (int i = 0; i < 16; ++i) o[i] = 0.0f;
  for (int d = 0; d < 64; ++d) {
    float qd = qs[pos][d];
#pragma unroll
    for (int i4 = 0; i4 < 4; ++i4) {
      float4 c4 = *(const float4*)&Cm[d][s * 16 + i4 * 4];
      o[i4 * 4 + 0] += qd * c4.x;
      o[i4 * 4 + 1] += qd * c4.y;
      o[i4 * 4 + 2] += qd * c4.z;
      o[i4 * 4 + 3] += qd * c4.w;
    }
  }
  u16* orow = att + (size_t)(batch * SEQ + u * 64 + pos) * DIM + head * DH + s * 16;
  uint4 pk0, pk1;
  pk0.x = (unsigned)f2b(o[0] * Dinv) | ((unsigned)f2b(o[1] * Dinv) << 16);
  pk0.y = (unsigned)f2b(o[2] * Dinv) | ((unsigned)f2b(o[3] * Dinv) << 16);
  pk0.z = (unsigned)f2b(o[4] * Dinv) | ((unsigned)f2b(o[5] * Dinv) << 16);
  pk0.w = (unsigned)f2b(o[6] * Dinv) | ((unsigned)f2b(o[7] * Dinv) << 16);
  pk1.x = (unsigned)f2b(o[8] * Dinv) | ((unsigned)f2b(o[9] * Dinv) << 16);
  pk1.y = (unsigned)f2b(o[10] * Dinv) | ((unsigned)f2b(o[11] * Dinv) << 16);
  pk1.z = (unsigned)f2b(o[12] * Dinv) | ((unsigned)f2b(o[13] * Dinv) << 16);
  pk1.w = (unsigned)f2b(o[14] * Dinv) | ((unsigned)f2b(o[15] * Dinv) << 16);
  *(uint4*)orow = pk0;
  *(uint4*)(orow + 8) = pk1;
}

// ---------------- host orchestration ----------------
extern "C" void kernel_launch(void* const* d_in, const int* in_sizes, int n_in,
                              void* d_out, int out_size, void* d_ws, size_t ws_size,
                              hipStream_t stream) {
  (void)in_sizes; (void)n_in; (void)out_size; (void)ws_size;
  const void* x_in = d_in[0];
  const void* ln1_g = d_in[1];
  const void* ln1_b = d_in[2];
  const void* wq = d_in[3];
  const void* wk = d_in[4];
  const void* wv = d_in[5];
  const void* wo = d_in[6];
  const void* bo = d_in[7];
  const void* ln2_g = d_in[8];
  const void* ln2_b = d_in[9];
  const void* w1 = d_in[10];
  const void* b1 = d_in[11];
  const void* w2 = d_in[12];
  const void* b2 = d_in[13];

  char* ws = (char*)d_ws;
  float* xf = (float*)(ws);              // 16 MiB f32 residual
  u16* h = (u16*)(ws + 16777216);        // 8 MiB bf16
  u16* region = (u16*)(ws + 25165824);   // 32 MiB: qkv (24 MiB) / gb (32 MiB)
  float* Ksum = (float*)(ws + 58720256); // 256 KiB
  float* KV = (float*)(ws + 58982400);   // 16 MiB
  u16* WR = (u16*)(ws + 75759616);       // 24 MiB repacked weights
  int* dt = (int*)(ws + 100925440);      // dtype flag
  u16* qkv = region;
  u16* gb = region;

  auto WqkvR = [&](int i) { return WR + (size_t)i * LSTRIDE + 0; };
  auto WoR   = [&](int i) { return WR + (size_t)i * LSTRIDE + 786432; };
  auto W1R   = [&](int i) { return WR + (size_t)i * LSTRIDE + 1048576; };
  auto W2R   = [&](int i) { return WR + (size_t)i * LSTRIDE + 2097152; };

  k_detect<<<dim3(1), dim3(1), 0, stream>>>(ln1_g, dt);

  const int nx = ROWS * DIM;
  k_x2f<<<dim3((nx + 255) / 256), dim3(256), 0, stream>>>(x_in, xf, nx, dt);

  k_repackQ<<<dim3(16, 8, 16), dim3(256), 0, stream>>>(wq, wk, wv, wo, WR, dt);
  k_repackF1<<<dim3(16, 32, 4), dim3(256), 0, stream>>>(w1, WR, dt);
  k_repackF2<<<dim3(64, 8, 4), dim3(256), 0, stream>>>(w2, WR, dt);

  for (int i = 0; i < 4; ++i) {
    // PreNorm(attn)
    k_ln<<<dim3(ROWS), dim3(256), 0, stream>>>(xf, ln1_g, ln1_b, (long)i * DIM, h, dt);
    // fused QKV gemm: [8192,512] @ [512,1536] — staggered 4-phase pipeline
    k_gemm8<false, false><<<dim3(32, 6), dim3(512), 0, stream>>>(
        h, WqkvR(i), nullptr, 0, qkv, QKVW, DIM, dt);
    k_attnA<<<dim3(1024), dim3(256), 0, stream>>>(qkv, Ksum, KV);
    k_scan2<<<dim3(1024), dim3(64), 0, stream>>>(Ksum, KV);
    k_attnC<<<dim3(1024), dim3(256), 0, stream>>>(qkv, Ksum, KV, h);  // att -> h
    // x += att @ wo + bo  (N=512: stays on 128-tile kernel)
    k_gemm3<2, true, false, true, true><<<dim3(64, 8), dim3(256), 0, stream>>>(
        h, WoR(i), bo, (long)i * DIM, xf, xf, ROWS, DIM, DIM, dt);
    // PreNorm(FF)
    k_ln<<<dim3(ROWS), dim3(256), 0, stream>>>(xf, ln2_g, ln2_b, (long)i * DIM, h, dt);
    // FF up: [8192,512] @ [512,2048] + bias + gelu — staggered 4-phase pipeline
    k_gemm8<true, true><<<dim3(32, 8), dim3(512), 0, stream>>>(
        h, W1R(i), b1, (long)i * FFDIM, gb, FFDIM, DIM, dt);
    // FF down: [8192,2048] @ [2048,512] + bias + residual (N=512: stays on 128-tile)
    k_gemm3<2, true, false, true, true><<<dim3(64, 8), dim3(256), 0, stream>>>(
        gb, W2R(i), b2, (long)i * DIM, xf, xf, ROWS, DIM, FFDIM, dt);
  }

  k_store<<<dim3((nx + 255) / 256), dim3(256), 0, stream>>>(xf, d_out, nx, dt);
}

// Round 3
// 854.079 us; speedup vs baseline: 1.0307x; 1.0219x over previous
//
#include <hip/hip_runtime.h>

// ---------------- types / helpers ----------------
typedef unsigned short u16;
typedef __bf16 bf16x8 __attribute__((ext_vector_type(8)));
typedef float floatx4 __attribute__((ext_vector_type(4)));

#define DIM 512
#define HEADS 8
#define DH 64
#define SEQ 4096
#define BATCH 2
#define ROWS (BATCH * SEQ) /* 8192 */
#define FFDIM 2048
#define QKVW 1536 /* fused qkv row width */
#define LSTRIDE 3145728L /* repacked weight elems per layer */

__device__ __forceinline__ float b2f(u16 u) {
  union { float f; unsigned int i; } c; c.i = ((unsigned int)u) << 16; return c.f;
}
__device__ __forceinline__ u16 f2b(float f) {
  union { float f; unsigned int i; } c; c.f = f;
  unsigned int r = c.i + 0x7FFFu + ((c.i >> 16) & 1u);
  return (u16)(r >> 16);
}
__device__ __forceinline__ float ldin(const void* p, long i, int bf) {
  return bf ? b2f(((const u16*)p)[i]) : ((const float*)p)[i];
}
// async global->LDS, 16 bytes/lane. LDS dest = base + lane*16 (HW); global addr per-lane.
__device__ __forceinline__ void ld16(const u16* g, u16* l) {
  __builtin_amdgcn_global_load_lds((const __attribute__((address_space(1))) void*)g,
                                   (__attribute__((address_space(3))) void*)l, 16, 0, 0);
}
// unpack 8 u16 (as uint4) -> 8 floats
__device__ __forceinline__ void unpk8(uint4 p, float* o) {
  o[0] = b2f((u16)(p.x & 0xFFFF)); o[1] = b2f((u16)(p.x >> 16));
  o[2] = b2f((u16)(p.y & 0xFFFF)); o[3] = b2f((u16)(p.y >> 16));
  o[4] = b2f((u16)(p.z & 0xFFFF)); o[5] = b2f((u16)(p.z >> 16));
  o[6] = b2f((u16)(p.w & 0xFFFF)); o[7] = b2f((u16)(p.w >> 16));
}
// exact-enough GELU: erf via Abramowitz-Stegun 7.1.26 (|err| <= 1.5e-7) + fast exp.
__device__ __forceinline__ float fast_gelu(float v) {
  float z = fabsf(v) * 0.70710678118654752f;
  float t = 1.0f / (1.0f + 0.3275911f * z);
  float p = t * (0.254829592f +
           t * (-0.284496736f +
           t * (1.421413741f +
           t * (-1.453152027f +
           t * 1.061405429f))));
  float e = __expf(-z * z);
  float er = 1.0f - p * e;             // erf(|z|)
  float s = copysignf(er, v);          // erf(z)
  return 0.5f * v * (1.0f + s);
}

// ---------------- dtype detection ----------------
__global__ void k_detect(const void* __restrict__ g, int* __restrict__ flag) {
  *flag = (((const u16*)g)[0] == 0x3F80u) ? 1 : 0;
}

// ---------------- input x -> f32 / f32 -> out ----------------
__global__ __launch_bounds__(256) void k_x2f(const void* __restrict__ in, float* __restrict__ out,
                                             int n, const int* __restrict__ dt) {
  int bf = *dt;
  int i = blockIdx.x * 256 + threadIdx.x;
  if (i < n) out[i] = ldin(in, i, bf);
}
__global__ __launch_bounds__(256) void k_store(const float* __restrict__ in, void* __restrict__ out,
                                               int n, const int* __restrict__ dt) {
  int bf = *dt;
  int i = blockIdx.x * 256 + threadIdx.x;
  if (i < n) {
    if (bf) ((u16*)out)[i] = f2b(in[i]);
    else ((float*)out)[i] = in[i];
  }
}

// ---------------- weight repack (LDS-tiled, coalesced, batched) ----------------
__device__ __forceinline__ void repack_tile(const void* W, long w_off, u16* R, int N,
                                            int n16tot, int j_off, int kb, int jb, int bf) {
  int t = threadIdx.x;
  __shared__ float tile[32][65];
  int r0 = t >> 6;
  int c = t & 63;
#pragma unroll
  for (int i = 0; i < 8; ++i) {
    int rr = i * 4 + r0;
    tile[rr][c] = ldin(W, w_off + (long)(kb * 32 + rr) * N + jb * 64 + c, bf);
  }
  __syncthreads();
  int lane = t & 63, w = t >> 6;
  alignas(16) u16 tmp[8];
#pragma unroll
  for (int r = 0; r < 8; ++r) tmp[r] = f2b(tile[(lane >> 4) * 8 + r][w * 16 + (lane & 15)]);
  long oidx = (((long)kb * n16tot + j_off + jb * 4 + w) * 64 + lane) * 8;
  *(uint4*)(R + oidx) = *(const uint4*)tmp;
}
// all 512x512 weights: grid (16,8,16); z = layer*4 + type(0=q,1=k,2=v,3=o)
__global__ __launch_bounds__(256) void k_repackQ(const void* wq, const void* wk,
                                                 const void* wv, const void* wo,
                                                 u16* WR, const int* __restrict__ dt) {
  int bf = *dt;
  int z = blockIdx.z, layer = z >> 2, type = z & 3;
  const void* W = (type == 0) ? wq : (type == 1) ? wk : (type == 2) ? wv : wo;
  u16* R = WR + (long)layer * LSTRIDE + (type < 3 ? 0 : 786432);
  int n16tot = (type < 3) ? 96 : 32;
  int j_off = (type < 3) ? type * 32 : 0;
  repack_tile(W, (long)layer * 262144, R, 512, n16tot, j_off, blockIdx.x, blockIdx.y, bf);
}
// w1: grid (16,32,4)
__global__ __launch_bounds__(256) void k_repackF1(const void* w1, u16* WR, const int* __restrict__ dt) {
  int bf = *dt;
  repack_tile(w1, (long)blockIdx.z * 1048576, WR + (long)blockIdx.z * LSTRIDE + 1048576,
              2048, 128, 0, blockIdx.x, blockIdx.y, bf);
}
// w2: grid (64,8,4)
__global__ __launch_bounds__(256) void k_repackF2(const void* w2, u16* WR, const int* __restrict__ dt) {
  int bf = *dt;
  repack_tile(w2, (long)blockIdx.z * 1048576, WR + (long)blockIdx.z * LSTRIDE + 2097152,
              512, 32, 0, blockIdx.x, blockIdx.y, bf);
}

// ---------------- layernorm (f32 in, bf16 out) ----------------
__global__ __launch_bounds__(256) void k_ln(const float* __restrict__ x,
                                            const void* __restrict__ g, const void* __restrict__ b,
                                            long gb_off, u16* __restrict__ out,
                                            const int* __restrict__ dt) {
  int bf = *dt;
  int row = blockIdx.x;
  int t = threadIdx.x;
  const float* xr = x + (size_t)row * DIM;
  float v0 = xr[t], v1 = xr[t + 256];
  float s = v0 + v1;
  float s2 = v0 * v0 + v1 * v1;
#pragma unroll
  for (int off = 32; off > 0; off >>= 1) {
    s += __shfl_down(s, off);
    s2 += __shfl_down(s2, off);
  }
  __shared__ float red[8];
  int lane = t & 63, w = t >> 6;
  if (lane == 0) { red[w] = s; red[4 + w] = s2; }
  __syncthreads();
  float ts = red[0] + red[1] + red[2] + red[3];
  float ts2 = red[4] + red[5] + red[6] + red[7];
  float mean = ts * (1.0f / DIM);
  float var = ts2 * (1.0f / DIM) - mean * mean;
  float rstd = rsqrtf(var + 1e-5f);
  u16* orow = out + (size_t)row * DIM;
  orow[t] = f2b((v0 - mean) * rstd * ldin(g, gb_off + t, bf) + ldin(b, gb_off + t, bf));
  orow[t + 256] = f2b((v1 - mean) * rstd * ldin(g, gb_off + t + 256, bf) + ldin(b, gb_off + t + 256, bf));
}

// ---------------- MFMA GEMM v3.1 (N=512 GEMMs: WO, W2) — BK=64, half the drains ----
// C[M,N] = A[M,K] @ W[K,N] (+bias,+gelu,+res). Block 256 = 4 waves 2(m)x2(n);
// block tile = 128 x NJ*32; per iter stages BK=64 (2 kk halves), one barrier-drain.
template <int NJ, bool HAS_BIAS, bool DO_GELU, bool HAS_RES, bool OUT_F32>
__global__ __launch_bounds__(256) void k_gemm3(const u16* __restrict__ A, const u16* __restrict__ BR,
                                               const void* bias, long bias_off,
                                               const float* res, void* outp,
                                               int M, int N, int K, const int* dtflag) {
  int lane = threadIdx.x & 63;
  int wid = threadIdx.x >> 6;
  int wm = wid & 1, wn = wid >> 1;
  int m0 = blockIdx.x * 128;
  int n0 = blockIdx.y * (NJ * 32);
  int n16 = N >> 4;
  int n016 = n0 >> 4;

  constexpr int BUFB = (16 + 4 * NJ) * 1024;  // A 16KB + B NJ*4KB per buffer
  __shared__ alignas(16) char smem[2 * BUFB];

  floatx4 acc[4][NJ];
#pragma unroll
  for (int mi = 0; mi < 4; ++mi)
#pragma unroll
    for (int j = 0; j < NJ; ++j)
#pragma unroll
      for (int r = 0; r < 4; ++r) acc[mi][j][r] = 0.0f;

  // A gather (fragment-order): lane l covers row m0 + wid*32 + (l&15) (+16), chunk (l>>4)*8
  const u16* Ag = A + ((size_t)(m0 + wid * 32 + (lane & 15)) * K + ((lane >> 4) * 8));
  int nKB = K >> 6;

  auto stage = [&](int kb, int b) {
    u16* aL = (u16*)(smem + b * BUFB);
    u16* bL = aL + 8192;
    const u16* s = Ag + (size_t)kb * 64;
    ld16(s,                        aL + (wid * 2) * 512);            // kk0, rows lo
    ld16(s + (size_t)16 * K,       aL + (wid * 2 + 1) * 512);        // kk0, rows hi
    ld16(s + 32,                   aL + 4096 + (wid * 2) * 512);     // kk1, rows lo
    ld16(s + (size_t)16 * K + 32,  aL + 4096 + (wid * 2 + 1) * 512); // kk1, rows hi
#pragma unroll
    for (int sj = 0; sj < NJ / 2; ++sj) {
      int jg = wid * (NJ / 2) + sj;
      ld16(BR + (((size_t)(kb * 2) * n16 + n016 + jg) * 64 + lane) * 8, bL + jg * 512);
      ld16(BR + (((size_t)(kb * 2 + 1) * n16 + n016 + jg) * 64 + lane) * 8,
           bL + NJ * 1024 + jg * 512);
    }
  };

  stage(0, 0);
  for (int kb = 0; kb < nKB; ++kb) {
    __syncthreads();  // compiler drains vmcnt: stage(kb) complete, prev reads done
    if (kb + 1 < nKB) stage(kb + 1, (kb + 1) & 1);
    const u16* aL = (const u16*)(smem + (kb & 1) * BUFB);
    const u16* bL = aL + 8192;
#pragma unroll
    for (int h = 0; h < 2; ++h) {
      bf16x8 afr[4], bfr[NJ];
#pragma unroll
      for (int mi = 0; mi < 4; ++mi)
        afr[mi] = *(const bf16x8*)(aL + h * 4096 + ((wm * 4 + mi) * 64 + lane) * 8);
#pragma unroll
      for (int j = 0; j < NJ; ++j)
        bfr[j] = *(const bf16x8*)(bL + h * NJ * 1024 + ((wn * NJ + j) * 64 + lane) * 8);
#pragma unroll
      for (int mi = 0; mi < 4; ++mi)
#pragma unroll
        for (int j = 0; j < NJ; ++j)
          acc[mi][j] = __builtin_amdgcn_mfma_f32_16x16x32_bf16(afr[mi], bfr[j], acc[mi][j], 0, 0, 0);
    }
  }

  // ---- epilogue: per-wave LDS transpose -> coalesced vector stores ----
  __syncthreads();
  constexpr int EPS = 84;
  float* ep = (float*)smem + wid * (16 * EPS);
  constexpr int C = NJ * 16;
  int dtv = HAS_BIAS ? *dtflag : 0;
  int nW = n0 + wn * C;
  int mWbase = m0 + wm * 64;

#pragma unroll
  for (int mi = 0; mi < 4; ++mi) {
#pragma unroll
    for (int j = 0; j < NJ; ++j) {
      float bv = HAS_BIAS ? ldin(bias, bias_off + nW + j * 16 + (lane & 15), dtv) : 0.0f;
#pragma unroll
      for (int r = 0; r < 4; ++r) {
        float v = acc[mi][j][r] + bv;
        if (DO_GELU) v = fast_gelu(v);
        ep[((lane >> 4) * 4 + r) * EPS + j * 16 + (lane & 15)] = v;
      }
    }
    __builtin_amdgcn_s_waitcnt(0);
    if (OUT_F32) {
      constexpr int LPR = C / 4;
      constexpr int RPP = 64 / LPR;
      constexpr int NP = 16 / RPP;
#pragma unroll
      for (int p = 0; p < NP; ++p) {
        int row = p * RPP + lane / LPR;
        int cb = (lane % LPR) * 4;
        float4 v = *(const float4*)&ep[row * EPS + cb];
        size_t gi = (size_t)(mWbase + mi * 16 + row) * N + nW + cb;
        if (HAS_RES) {
          float4 rv = *(const float4*)&res[gi];
          v.x += rv.x; v.y += rv.y; v.z += rv.z; v.w += rv.w;
        }
        *(float4*)&((float*)outp)[gi] = v;
      }
    } else {
      constexpr int LPR = C / 8;
      constexpr int RPP = 64 / LPR;
      constexpr int NP = 16 / RPP;
#pragma unroll
      for (int p = 0; p < NP; ++p) {
        int row = p * RPP + lane / LPR;
        int cb = (lane % LPR) * 8;
        const float* er = &ep[row * EPS + cb];
        uint4 pk;
        pk.x = (unsigned)f2b(er[0]) | ((unsigned)f2b(er[1]) << 16);
        pk.y = (unsigned)f2b(er[2]) | ((unsigned)f2b(er[3]) << 16);
        pk.z = (unsigned)f2b(er[4]) | ((unsigned)f2b(er[5]) << 16);
        pk.w = (unsigned)f2b(er[6]) | ((unsigned)f2b(er[7]) << 16);
        size_t gi = (size_t)(mWbase + mi * 16 + row) * N + nW + cb;
        *(uint4*)&((u16*)outp)[gi] = pk;
      }
    }
    __builtin_amdgcn_s_waitcnt(0);
  }
}

// ---------------- MFMA GEMM v4.3: 256x256 pipeline, COALESCED swizzled A-staging ----
// Block 512 = 8 waves (2m x 4n); tile 256x256; K-tile 64; 4 phases/K-tile.
// A-staging fix (the round-2 theory): previous fragment-order A gather read 16
// scattered 64B segments per instruction (half-L2-line granule -> ~40% of L2 BW).
// Now A stages CONTIGUOUS 1KB per instruction (8 rows x 128B) with the st-XOR
// swizzle applied on the per-lane GLOBAL source (rule #21: linear LDS dest +
// inverse-swizzled source + swizzled read):
//   physical u16 = row*64 + (cu ^ ((row&7)<<3));  stage lane i of inst covers
//   row = base+ (i>>3), cu = ((i&7) ^ ((i>>3)&7))*8  -> every aligned 4-lane group
//   reads one aligned contiguous 64B; whole inst = 1KB contiguous.
// ds_read side: addr = g*1024 + (lane&15)*64 + ((kk*32 + (lane>>4)*8) ^ ((lane&7)<<3))
//   -> lanes of a 16-group spread over all 32 banks, 2-way (free).
// B staging/reads unchanged (fragment-order, already contiguous + conflict-free).
//
// Schedule (counted vmcnt, never 0 in steady state):
//   ph0: read A(kk0,mh0)+B(kk0); stage A-half0(c+1)->idle | MFMA
//   ph1: read A(kk0,mh1);        stage A-half1(c+1)->idle | MFMA; vmcnt(4)
//   ph2: read A(kk1,mh0)+B(kk1); stage B-kk0(c+1)->idle   | MFMA
//   ph3: read A(kk1,mh1);        stage B-kk1(c+1)->idle   | MFMA; vmcnt(2)
// vmcnt(4) @ph1 guarantees B-kk1(c) landed (needed ph2); vmcnt(2) @ph3 guarantees
// A(c+1)+B-kk0(c+1) landed (needed next ph0); B-kk1(c+1) stays in flight.
template <bool HAS_BIAS, bool DO_GELU>
__global__ __launch_bounds__(512, 2) void k_gemm8(const u16* __restrict__ A, const u16* __restrict__ BR,
                                                  const void* bias, long bias_off,
                                                  u16* __restrict__ outp,
                                                  int N, int K, const int* dtflag) {
  int lane = threadIdx.x & 63;
  int w = threadIdx.x >> 6;       // wave 0..7
  int wm = w >> 2, wn = w & 3;    // 2 x 4
  int m0 = blockIdx.x * 256;
  int n0 = blockIdx.y * 256;
  int n16 = N >> 4;
  int n016 = n0 >> 4;
  int NKT = K >> 6;               // K-tiles of 64

  __shared__ alignas(16) u16 smem8[65536];  // 2 bufs x (A 32KB | B 32KB) = 128 KiB

  // ---- A staging bases (contiguous + pre-swizzled source) ----
  int arow = lane >> 3;                       // row within 8-row inst group
  int acu = ((lane & 7) ^ arow) * 8;          // pre-swizzled col (u16 units)
  const u16* Ag0 = A + (size_t)(m0 + (w * 2 + 0) * 8 + arow) * K + acu;
  const u16* Ag1 = A + (size_t)(m0 + (w * 2 + 1) * 8 + arow) * K + acu;
  const u16* Bg = BR + (size_t)n016 * 512 + lane * 8;

  // stage A half (rows half*128..+127) of K-tile kt: 2 x 1KB contiguous insts
  auto stA = [&](int kt, int half, int dbuf) {
    u16* dst = smem8 + dbuf * 32768 + half * 8192;
    size_t go = (size_t)half * 128 * K + (size_t)kt * 64;
    ld16(Ag0 + go, dst + (w * 2 + 0) * 512);
    ld16(Ag1 + go, dst + (w * 2 + 1) * 512);
  };
  // stage B kk-half of K-tile kt: 2 insts (col-groups j=w, j=8+w)
  auto stB = [&](int kt, int kk, int dbuf) {
    u16* dst = smem8 + dbuf * 32768 + 16384 + kk * 8192;
    const u16* s = Bg + ((size_t)(kt * 2 + kk) * n16) * 512;
    ld16(s + (size_t)w * 512,       dst + (0 + w) * 512);
    ld16(s + (size_t)(8 + w) * 512, dst + (8 + w) * 512);
  };

  // per-lane swizzled A-read offsets (u16 units)
  int aoff = (lane & 15) * 64;
  int axor = (lane & 7) << 3;
  int ak0 = (((lane >> 4) * 8)) ^ axor;        // kk0 col part
  int ak1 = ((32 + (lane >> 4) * 8)) ^ axor;   // kk1 col part

  floatx4 acc[8][4];
#pragma unroll
  for (int mi = 0; mi < 8; ++mi)
#pragma unroll
    for (int j = 0; j < 4; ++j)
#pragma unroll
      for (int r = 0; r < 4; ++r) acc[mi][j][r] = 0.0f;

  // ---- prologue: K-tile 0 fully staged; leave B-kk1(0) in flight ----
  stA(0, 0, 0);
  stA(0, 1, 0);
  stB(0, 0, 0);
  stB(0, 1, 0);
  asm volatile("s_waitcnt vmcnt(2)" ::: "memory");
  __builtin_amdgcn_s_barrier();

  for (int c = 0; c < NKT; ++c) {
    int buf = c & 1;
    const u16* aL = smem8 + buf * 32768;
    const u16* bL = aL + 16384;
    int kt1 = (c + 1 < NKT) ? c + 1 : NKT - 1;  // clamped (dummy re-stage at tail)
    bf16x8 afr[4], bfr[4];

    // ---- phase 0: (kk0, mh0) ----
#pragma unroll
    for (int i = 0; i < 4; ++i)
      afr[i] = *(const bf16x8*)(aL + (wm * 8 + i) * 1024 + aoff + ak0);
#pragma unroll
    for (int i = 0; i < 4; ++i)
      bfr[i] = *(const bf16x8*)(bL + ((wn * 4 + i) * 64 + lane) * 8);
    stA(kt1, 0, buf ^ 1);
    __builtin_amdgcn_s_barrier();
    asm volatile("s_waitcnt lgkmcnt(0)" ::: "memory");
    __builtin_amdgcn_s_setprio(1);
#pragma unroll
    for (int mi = 0; mi < 4; ++mi)
#pragma unroll
      for (int j = 0; j < 4; ++j)
        acc[mi][j] = __builtin_amdgcn_mfma_f32_16x16x32_bf16(afr[mi], bfr[j], acc[mi][j], 0, 0, 0);
    __builtin_amdgcn_s_setprio(0);
    __builtin_amdgcn_s_barrier();

    // ---- phase 1: (kk0, mh1) ----
#pragma unroll
    for (int i = 0; i < 4; ++i)
      afr[i] = *(const bf16x8*)(aL + (wm * 8 + 4 + i) * 1024 + aoff + ak0);
    stA(kt1, 1, buf ^ 1);
    __builtin_amdgcn_s_barrier();
    asm volatile("s_waitcnt lgkmcnt(0)" ::: "memory");
    __builtin_amdgcn_s_setprio(1);
#pragma unroll
    for (int mi = 0; mi < 4; ++mi)
#pragma unroll
      for (int j = 0; j < 4; ++j)
        acc[4 + mi][j] = __builtin_amdgcn_mfma_f32_16x16x32_bf16(afr[mi], bfr[j], acc[4 + mi][j], 0, 0, 0);
    __builtin_amdgcn_s_setprio(0);
    // B-kk1(c) (staged last iter) must land before ph2 reads; 4 younger loads fly on
    asm volatile("s_waitcnt vmcnt(4)" ::: "memory");
    __builtin_amdgcn_s_barrier();

    // ---- phase 2: (kk1, mh0) ----
#pragma unroll
    for (int i = 0; i < 4; ++i)
      afr[i] = *(const bf16x8*)(aL + (wm * 8 + i) * 1024 + aoff + ak1);
#pragma unroll
    for (int i = 0; i < 4; ++i)
      bfr[i] = *(const bf16x8*)(bL + ((16 + wn * 4 + i) * 64 + lane) * 8);
    stB(kt1, 0, buf ^ 1);
    __builtin_amdgcn_s_barrier();
    asm volatile("s_waitcnt lgkmcnt(0)" ::: "memory");
    __builtin_amdgcn_s_setprio(1);
#pragma unroll
    for (int mi = 0; mi < 4; ++mi)
#pragma unroll
      for (int j = 0; j < 4; ++j)
        acc[mi][j] = __builtin_amdgcn_mfma_f32_16x16x32_bf16(afr[mi], bfr[j], acc[mi][j], 0, 0, 0);
    __builtin_amdgcn_s_setprio(0);
    __builtin_amdgcn_s_barrier();

    // ---- phase 3: (kk1, mh1) ----
#pragma unroll
    for (int i = 0; i < 4; ++i)
      afr[i] = *(const bf16x8*)(aL + (wm * 8 + 4 + i) * 1024 + aoff + ak1);
    stB(kt1, 1, buf ^ 1);
    __builtin_amdgcn_s_barrier();
    asm volatile("s_waitcnt lgkmcnt(0)" ::: "memory");
    __builtin_amdgcn_s_setprio(1);
#pragma unroll
    for (int mi = 0; mi < 4; ++mi)
#pragma unroll
      for (int j = 0; j < 4; ++j)
        acc[4 + mi][j] = __builtin_amdgcn_mfma_f32_16x16x32_bf16(afr[mi], bfr[j], acc[4 + mi][j], 0, 0, 0);
    __builtin_amdgcn_s_setprio(0);
    // A(c+1) + B-kk0(c+1) must land before next ph0; B-kk1(c+1) stays in flight
    asm volatile("s_waitcnt vmcnt(2)" ::: "memory");
    __builtin_amdgcn_s_barrier();
  }

  // drain tail stages before reusing LDS
  asm volatile("s_waitcnt vmcnt(0)" ::: "memory");
  __builtin_amdgcn_s_barrier();

  // ---- epilogue: per-wave LDS transpose -> coalesced bf16 stores ----
  constexpr int EPS = 68;
  float* ep = (float*)smem8 + w * (16 * EPS);
  int dtv = HAS_BIAS ? *dtflag : 0;
  int nW = n0 + wn * 64;
  int mW = m0 + wm * 128;

#pragma unroll
  for (int mf = 0; mf < 8; ++mf) {
#pragma unroll
    for (int j = 0; j < 4; ++j) {
      float bv = HAS_BIAS ? ldin(bias, bias_off + nW + j * 16 + (lane & 15), dtv) : 0.0f;
#pragma unroll
      for (int r = 0; r < 4; ++r) {
        float v = acc[mf][j][r] + bv;
        if (DO_GELU) v = fast_gelu(v);
        ep[((lane >> 4) * 4 + r) * EPS + j * 16 + (lane & 15)] = v;
      }
    }
    asm volatile("s_waitcnt lgkmcnt(0)" ::: "memory");
#pragma unroll
    for (int p = 0; p < 2; ++p) {
      int row = p * 8 + (lane >> 3);
      int cb = (lane & 7) * 8;
      const float* er = &ep[row * EPS + cb];
      uint4 pk;
      pk.x = (unsigned)f2b(er[0]) | ((unsigned)f2b(er[1]) << 16);
      pk.y = (unsigned)f2b(er[2]) | ((unsigned)f2b(er[3]) << 16);
      pk.z = (unsigned)f2b(er[4]) | ((unsigned)f2b(er[5]) << 16);
      pk.w = (unsigned)f2b(er[6]) | ((unsigned)f2b(er[7]) << 16);
      size_t gi = (size_t)(mW + mf * 16 + row) * N + nW + cb;
      *(uint4*)&outp[gi] = pk;
    }
    asm volatile("s_waitcnt lgkmcnt(0)" ::: "memory");
  }
}

// ---------------- attention phase A: per-bucket exp(k)^T v and key sums ----------------
__global__ __launch_bounds__(256) void k_attnA(const u16* __restrict__ qkv,
                                               float* __restrict__ Ksum, float* __restrict__ KV) {
  int u = blockIdx.x & 63;
  int bh = blockIdx.x >> 6;
  int head = bh & 7, batch = bh >> 3;
  int t = threadIdx.x;
  int pr = t >> 2, s = t & 3;
  __shared__ float kex[64][68];
  __shared__ float vv[64][68];
  const u16* base = qkv + (size_t)(batch * SEQ + u * 64 + pr) * QKVW + head * DH;
  uint4 kp0 = *(const uint4*)(base + 512 + s * 16);
  uint4 kp1 = *(const uint4*)(base + 512 + s * 16 + 8);
  uint4 vp0 = *(const uint4*)(base + 1024 + s * 16);
  uint4 vp1 = *(const uint4*)(base + 1024 + s * 16 + 8);
  float kf[16], vf[16];
  unpk8(kp0, kf); unpk8(kp1, kf + 8);
  unpk8(vp0, vf); unpk8(vp1, vf + 8);
#pragma unroll
  for (int i = 0; i < 16; ++i) {
    kex[pr][s * 16 + i] = expf(fminf(kf[i], 30.0f));
    vv[pr][s * 16 + i] = vf[i];
  }
  __syncthreads();
  int d = pr;
  float acc[16];
#pragma unroll
  for (int i = 0; i < 16; ++i) acc[i] = 0.0f;
  float ks = 0.0f;
  for (int p = 0; p < 64; ++p) {
    float kp = kex[p][d];
    ks += kp;
#pragma unroll
    for (int i4 = 0; i4 < 4; ++i4) {
      float4 v4 = *(const float4*)&vv[p][s * 16 + i4 * 4];
      acc[i4 * 4 + 0] += kp * v4.x;
      acc[i4 * 4 + 1] += kp * v4.y;
      acc[i4 * 4 + 2] += kp * v4.z;
      acc[i4 * 4 + 3] += kp * v4.w;
    }
  }
  float* kvout = KV + (size_t)blockIdx.x * 4096 + d * 64 + s * 16;
#pragma unroll
  for (int i4 = 0; i4 < 4; ++i4) {
    float4 o; o.x = acc[i4 * 4]; o.y = acc[i4 * 4 + 1]; o.z = acc[i4 * 4 + 2]; o.w = acc[i4 * 4 + 3];
    *(float4*)(kvout + i4 * 4) = o;
  }
  if (s == 0) Ksum[(size_t)blockIdx.x * 64 + d] = ks;
}

// ---------------- attention phase B: exclusive prefix over buckets ----------------
// grid 1024 = bh*64 + d ; block 64 (thread = e). Register-batched: 64 loads issued
// at once (one latency trip), register prefix-sum, 64 stores — replaces the 64-deep
// dependent load->store round-trip chain.
__global__ __launch_bounds__(64) void k_scan2(float* __restrict__ Ksum, float* __restrict__ KV) {
  int bh = blockIdx.x >> 6;
  int d = blockIdx.x & 63;
  int e = threadIdx.x;
  float* p0 = KV + (size_t)bh * 64 * 4096 + d * 64 + e;
  float v[64];
#pragma unroll
  for (int u = 0; u < 64; ++u) v[u] = p0[(size_t)u * 4096];
  float run = 0.0f;
#pragma unroll
  for (int u = 0; u < 64; ++u) { float c = v[u]; v[u] = run; run += c; }
#pragma unroll
  for (int u = 0; u < 64; ++u) p0[(size_t)u * 4096] = v[u];
  if (d == 0) {
    float* kp = Ksum + (size_t)bh * 4096 + e;
    float sv[64];
#pragma unroll
    for (int u = 0; u < 64; ++u) sv[u] = kp[u * 64];
    float r = 0.0f;
#pragma unroll
    for (int u = 0; u < 64; ++u) { float c = sv[u]; sv[u] = r; r += c; }
#pragma unroll
    for (int u = 0; u < 64; ++u) kp[u * 64] = sv[u];
  }
}

// ---------------- attention phase C: softmax(q), D, output ----------------
__global__ __launch_bounds__(256) void k_attnC(const u16* __restrict__ qkv, const float* __restrict__ Ksum,
                                               const float* __restrict__ KV, u16* __restrict__ att) {
  int u = blockIdx.x & 63;
  int bh = blockIdx.x >> 6;
  int head = bh & 7, batch = bh >> 3;
  int t = threadIdx.x;
  int pos = t >> 2, s = t & 3;
  __shared__ float Cm[64][68];
  __shared__ float qs[64][68];
  __shared__ float S[64];
  const float* kvb = KV + (size_t)blockIdx.x * 4096 + pos * 64 + s * 16;
#pragma unroll
  for (int i4 = 0; i4 < 4; ++i4)
    *(float4*)&Cm[pos][s * 16 + i4 * 4] = *(const float4*)(kvb + i4 * 4);
  if (t < 64) S[t] = Ksum[(size_t)blockIdx.x * 64 + t];
  size_t grow = (size_t)(batch * SEQ + u * 64 + pos) * QKVW + head * DH;
  uint4 q0 = *(const uint4*)(qkv + grow + s * 16);
  uint4 q1 = *(const uint4*)(qkv + grow + s * 16 + 8);
  float q[16];
  unpk8(q0, q); unpk8(q1, q + 8);
  float mx = q[0];
#pragma unroll
  for (int i = 1; i < 16; ++i) mx = fmaxf(mx, q[i]);
  mx = fmaxf(mx, __shfl_xor(mx, 1));
  mx = fmaxf(mx, __shfl_xor(mx, 2));
  float sum = 0.0f;
#pragma unroll
  for (int i = 0; i < 16; ++i) { q[i] = expf(q[i] - mx); sum += q[i]; }
  sum += __shfl_xor(sum, 1);
  sum += __shfl_xor(sum, 2);
  float scale = 0.125f / sum;  // * e^-0.5 with e=64
  __syncthreads();  // S ready
  float Dp = 0.0f;
#pragma unroll
  for (int i = 0; i < 16; ++i) { q[i] *= scale; Dp += q[i] * S[s * 16 + i]; }
  Dp += __shfl_xor(Dp, 1);
  Dp += __shfl_xor(Dp, 2);
  float Dinv = 1.0f / fmaxf(Dp, 1e-3f);
#pragma unroll
  for (int i = 0; i < 16; ++i) qs[pos][s * 16 + i] = q[i];
  __syncthreads();  // Cm + qs ready
  float o[16];
#pragma unroll
  for (int i = 0; i < 16; ++i) o[i] = 0.0f;
  for (int d = 0; d < 64; ++d) {
    float qd = qs[pos][d];
#pragma unroll
    for (int i4 = 0; i4 < 4; ++i4) {
      float4 c4 = *(const float4*)&Cm[d][s * 16 + i4 * 4];
      o[i4 * 4 + 0] += qd * c4.x;
      o[i4 * 4 + 1] += qd * c4.y;
      o[i4 * 4 + 2] += qd * c4.z;
      o[i4 * 4 + 3] += qd * c4.w;
    }
  }
  u16* orow = att + (size_t)(batch * SEQ + u * 64 + pos) * DIM + head * DH + s * 16;
  uint4 pk0, pk1;
  pk0.x = (unsigned)f2b(o[0] * Dinv) | ((unsigned)f2b(o[1] * Dinv) << 16);
  pk0.y = (unsigned)f2b(o[2] * Dinv) | ((unsigned)f2b(o[3] * Dinv) << 16);
  pk0.z = (unsigned)f2b(o[4] * Dinv) | ((unsigned)f2b(o[5] * Dinv) << 16);
  pk0.w = (unsigned)f2b(o[6] * Dinv) | ((unsigned)f2b(o[7] * Dinv) << 16);
  pk1.x = (unsigned)f2b(o[8] * Dinv) | ((unsigned)f2b(o[9] * Dinv) << 16);
  pk1.y = (unsigned)f2b(o[10] * Dinv) | ((unsigned)f2b(o[11] * Dinv) << 16);
  pk1.z = (unsigned)f2b(o[12] * Dinv) | ((unsigned)f2b(o[13] * Dinv) << 16);
  pk1.w = (unsigned)f2b(o[14] * Dinv) | ((unsigned)f2b(o[15] * Dinv) << 16);
  *(uint4*)orow = pk0;
  *(uint4*)(orow + 8) = pk1;
}

// ---------------- host orchestration ----------------
extern "C" void kernel_launch(void* const* d_in, const int* in_sizes, int n_in,
                              void* d_out, int out_size, void* d_ws, size_t ws_size,
                              hipStream_t stream) {
  (void)in_sizes; (void)n_in; (void)out_size; (void)ws_size;
  const void* x_in = d_in[0];
  const void* ln1_g = d_in[1];
  const void* ln1_b = d_in[2];
  const void* wq = d_in[3];
  const void* wk = d_in[4];
  const void* wv = d_in[5];
  const void* wo = d_in[6];
  const void* bo = d_in[7];
  const void* ln2_g = d_in[8];
  const void* ln2_b = d_in[9];
  const void* w1 = d_in[10];
  const void* b1 = d_in[11];
  const void* w2 = d_in[12];
  const void* b2 = d_in[13];

  char* ws = (char*)d_ws;
  float* xf = (float*)(ws);              // 16 MiB f32 residual
  u16* h = (u16*)(ws + 16777216);        // 8 MiB bf16
  u16* region = (u16*)(ws + 25165824);   // 32 MiB: qkv (24 MiB) / gb (32 MiB)
  float* Ksum = (float*)(ws + 58720256); // 256 KiB
  float* KV = (float*)(ws + 58982400);   // 16 MiB
  u16* WR = (u16*)(ws + 75759616);       // 24 MiB repacked weights
  int* dt = (int*)(ws + 100925440);      // dtype flag
  u16* qkv = region;
  u16* gb = region;

  auto WqkvR = [&](int i) { return WR + (size_t)i * LSTRIDE + 0; };
  auto WoR   = [&](int i) { return WR + (size_t)i * LSTRIDE + 786432; };
  auto W1R   = [&](int i) { return WR + (size_t)i * LSTRIDE + 1048576; };
  auto W2R   = [&](int i) { return WR + (size_t)i * LSTRIDE + 2097152; };

  k_detect<<<dim3(1), dim3(1), 0, stream>>>(ln1_g, dt);

  const int nx = ROWS * DIM;
  k_x2f<<<dim3((nx + 255) / 256), dim3(256), 0, stream>>>(x_in, xf, nx, dt);

  k_repackQ<<<dim3(16, 8, 16), dim3(256), 0, stream>>>(wq, wk, wv, wo, WR, dt);
  k_repackF1<<<dim3(16, 32, 4), dim3(256), 0, stream>>>(w1, WR, dt);
  k_repackF2<<<dim3(64, 8, 4), dim3(256), 0, stream>>>(w2, WR, dt);

  for (int i = 0; i < 4; ++i) {
    // PreNorm(attn)
    k_ln<<<dim3(ROWS), dim3(256), 0, stream>>>(xf, ln1_g, ln1_b, (long)i * DIM, h, dt);
    // fused QKV gemm: [8192,512] @ [512,1536] — v4.3 coalesced-swizzled pipeline
    k_gemm8<false, false><<<dim3(32, 6), dim3(512), 0, stream>>>(
        h, WqkvR(i), nullptr, 0, qkv, QKVW, DIM, dt);
    k_attnA<<<dim3(1024), dim3(256), 0, stream>>>(qkv, Ksum, KV);
    k_scan2<<<dim3(1024), dim3(64), 0, stream>>>(Ksum, KV);
    k_attnC<<<dim3(1024), dim3(256), 0, stream>>>(qkv, Ksum, KV, h);  // att -> h
    // x += att @ wo + bo  (N=512, BK=64 gemm3)
    k_gemm3<2, true, false, true, true><<<dim3(64, 8), dim3(256), 0, stream>>>(
        h, WoR(i), bo, (long)i * DIM, xf, xf, ROWS, DIM, DIM, dt);
    // PreNorm(FF)
    k_ln<<<dim3(ROWS), dim3(256), 0, stream>>>(xf, ln2_g, ln2_b, (long)i * DIM, h, dt);
    // FF up: [8192,512] @ [512,2048] + bias + gelu — v4.3 pipeline
    k_gemm8<true, true><<<dim3(32, 8), dim3(512), 0, stream>>>(
        h, W1R(i), b1, (long)i * FFDIM, gb, FFDIM, DIM, dt);
    // FF down: [8192,2048] @ [2048,512] + bias + residual (N=512, BK=64 gemm3)
    k_gemm3<2, true, false, true, true><<<dim3(64, 8), dim3(256), 0, stream>>>(
        gb, W2R(i), b2, (long)i * DIM, xf, xf, ROWS, DIM, FFDIM, dt);
  }

  k_store<<<dim3((nx + 255) / 256), dim3(256), 0, stream>>>(xf, d_out, nx, dt);
}